// Round 1
// 681.050 us; speedup vs baseline: 1.0312x; 1.0312x over previous
//
#include <hip/hip_runtime.h>
#include <hip/hip_bf16.h>

#define Hn 8
#define Fn 768
#define Dn 128
#define En 256
#define Ln 13
#define Bn 8
#define Tn 1000
#define TPn 1024
#define NCOR 8128

typedef float f32x4 __attribute__((ext_vector_type(4)));
typedef __bf16 bf16x8 __attribute__((ext_vector_type(8)));
typedef unsigned short u16;

static __device__ __forceinline__ u16 f2bf(float f) {
  __hip_bfloat16 h = __float2bfloat16(f);
  return __builtin_bit_cast(u16, h);
}
static __device__ __forceinline__ float bf2f(u16 u) {
  return __bfloat162float(__builtin_bit_cast(__hip_bfloat16, u));
}

// async global->LDS, 16B per lane. LDS dest must be wave-uniform base; HW adds lane*16.
static __device__ __forceinline__ void gload_lds16(const u16* g, u16* lds_wave_base) {
  __builtin_amdgcn_global_load_lds(
      (const __attribute__((address_space(1))) unsigned int*)g,
      (__attribute__((address_space(3))) unsigned int*)lds_wave_base, 16, 0, 0);
}

// ---------------------------------------------------------------- k0: prep
__global__ __launch_bounds__(256) void k0_prep(
    const float* __restrict__ wk, const float* __restrict__ wv,
    const float* __restrict__ Wk, const float* __restrict__ Wv,
    float* __restrict__ kvw, u16* __restrict__ Wbf,
    float* __restrict__ s1, float* __restrict__ s2) {
  int gid = blockIdx.x * 256 + threadIdx.x;
  if (gid < 16) {
    int kv = gid >> 3, h = gid & 7;
    const float* w = (kv ? wv : wk) + h * Ln;
    float m = -1e30f;
    for (int l = 0; l < Ln; ++l) m = fmaxf(m, w[l]);
    float e[Ln], s = 0.f;
    for (int l = 0; l < Ln; ++l) { e[l] = expf(w[l] - m); s += e[l]; }
    for (int l = 0; l < Ln; ++l) kvw[(kv * Hn + h) * Ln + l] = e[l] / s;
  }
  int n = 2 * Hn * Dn * Fn;
  for (int i = gid; i < n; i += gridDim.x * 256) {
    float v = (i < Hn * Dn * Fn) ? Wk[i] : Wv[i - Hn * Dn * Fn];
    Wbf[i] = f2bf(v);
  }
  int ns = 2 * Bn * Hn * Dn;
  for (int i = gid; i < ns; i += gridDim.x * 256) { s1[i] = 0.f; s2[i] = 0.f; }
}

// ---------------------------------------------------------------- k1: l-reduce
// thread = (f-lane 0..31, t-quad 0..7): 13 float4 loads cover 4 consecutive t.
// res LDS [o][t][f+pad2] transpose; phase C: 4 lanes assemble one 64B row.
__global__ __launch_bounds__(256) void k1_raw(
    const float* __restrict__ x, const float* __restrict__ kvw_g,
    u16* __restrict__ kv_raw, int b0, int BG) {
  __shared__ float kvw[16 * Ln];
  __shared__ u16 res[16 * 32 * 34];  // 34816 B; row stride 34 (17 uints, odd)
  int tid = threadIdx.x;
  if (tid < 16 * Ln) kvw[tid] = kvw_g[tid];
  int f0 = blockIdx.x * 32, t0 = blockIdx.y * 32;
  int b_l = blockIdx.z, b = b0 + b_l;
  int fl = tid & 31, tq = tid >> 5;
  int tbase = t0 + tq * 4;
  bool valid = (tbase < Tn);  // Tn%4==0 -> quads never straddle
  float4 xq[13];
  if (valid) {
    const float4* xp = (const float4*)(x + ((size_t)(b * Fn + f0 + fl) * Tn + tbase) * Ln);
#pragma unroll
    for (int i = 0; i < 13; ++i) xq[i] = xp[i];
  }
  __syncthreads();
  const float* xf = (const float*)xq;
  for (int o = 0; o < 16; ++o) {
    float a0 = 0.f, a1 = 0.f, a2 = 0.f, a3 = 0.f;
    if (valid) {
#pragma unroll
      for (int l = 0; l < Ln; ++l) {
        float w = kvw[o * Ln + l];
        a0 += xf[l] * w;
        a1 += xf[Ln + l] * w;
        a2 += xf[2 * Ln + l] * w;
        a3 += xf[3 * Ln + l] * w;
      }
    }
    int rb = o * 1088 + tq * 4 * 34 + fl;
    res[rb] = f2bf(a0);
    res[rb + 34] = f2bf(a1);
    res[rb + 68] = f2bf(a2);
    res[rb + 102] = f2bf(a3);
  }
  __syncthreads();
  int part = tid & 3;
#pragma unroll
  for (int it = 0; it < 8; ++it) {
    int r = (tid >> 2) + it * 64;
    int o = r >> 5, tl = r & 31;
    int kv = o >> 3, h = o & 7;
    const u16* src = res + o * 1088 + tl * 34 + part * 8;
    uint4 v;
    v.x = *(const unsigned*)(src + 0);
    v.y = *(const unsigned*)(src + 2);
    v.z = *(const unsigned*)(src + 4);
    v.w = *(const unsigned*)(src + 6);
    u16* dst = kv_raw + (((size_t)(kv * BG + b_l) * Hn + h) * TPn + t0 + tl) * Fn + f0 + part * 8;
    *reinterpret_cast<uint4*>(dst) = v;
  }
}

// ---------------------------------------------------------------- k2: main GEMM
// 128x128 tile, BK=32, bf16 MFMA. 2-phase double-buffered async staging
// (1 barrier per K-step). Fused: scores = q.K for kv==0 tiles (kills k3a).
__global__ __launch_bounds__(256) void k2_gemm(
    const u16* __restrict__ kv_raw, const u16* __restrict__ Wbf,
    const float* __restrict__ bk, const float* __restrict__ bv,
    const float* __restrict__ qg,
    u16* __restrict__ mhT, float* __restrict__ s1buf, float* __restrict__ s2buf,
    float* __restrict__ scores, int b0, int BG) {
  __shared__ __align__(16) char ldsbuf[33280];
  __shared__ float qsh[Dn];
  u16* As0 = (u16*)ldsbuf;             // [128 t][32 f]  8KB
  u16* Bs0 = (u16*)(ldsbuf + 8192);    // [128 d][32 f]  8KB
  u16* As1 = (u16*)(ldsbuf + 16384);
  u16* Bs1 = (u16*)(ldsbuf + 24576);
  u16* Cst = (u16*)ldsbuf;             // [128 t][130] (reused after K-loop)
  int tid = threadIdx.x, lane = tid & 63, w = tid >> 6;
  int t0 = blockIdx.x * 128;
  int b_l = blockIdx.y / Hn, h = blockIdx.y % Hn, kv = blockIdx.z;
  int b = b0 + b_l;
  if (tid < Dn) qsh[tid] = qg[h * Dn + tid];
  const u16* Abase = kv_raw + ((size_t)(kv * BG + b_l) * Hn + h) * TPn * Fn + (size_t)t0 * Fn;
  const u16* Bbase = Wbf + ((size_t)(kv * Hn + h)) * Dn * Fn;
  f32x4 acc[4][4];
#pragma unroll
  for (int mi = 0; mi < 4; ++mi)
#pragma unroll
    for (int ni = 0; ni < 4; ++ni) acc[mi][ni] = (f32x4){0.f, 0.f, 0.f, 0.f};
  int wm = (w >> 1) * 64, wn = (w & 1) * 64;
  int lin0 = tid, lin1 = tid + 256;
  int row0 = lin0 >> 2, part0 = lin0 & 3;
  int row1 = lin1 >> 2, part1 = lin1 & 3;
  int wb0 = (w * 64) * 8, wb1 = (256 + w * 64) * 8;  // wave-uniform LDS elem base

  auto STAGE = [&](int f0, u16* Ad, u16* Bd) {
    gload_lds16(Abase + (size_t)row0 * Fn + f0 + part0 * 8, Ad + wb0);
    gload_lds16(Abase + (size_t)row1 * Fn + f0 + part1 * 8, Ad + wb1);
    gload_lds16(Bbase + (size_t)row0 * Fn + f0 + part0 * 8, Bd + wb0);
    gload_lds16(Bbase + (size_t)row1 * Fn + f0 + part1 * 8, Bd + wb1);
  };
  auto COMPUTE = [&](const u16* Ac, const u16* Bc) {
    bf16x8 af[4], bg[4];
#pragma unroll
    for (int mi = 0; mi < 4; ++mi)
      af[mi] = *(const bf16x8*)(Ac + (wm + mi * 16 + (lane & 15)) * 32 + (lane >> 4) * 8);
#pragma unroll
    for (int ni = 0; ni < 4; ++ni)
      bg[ni] = *(const bf16x8*)(Bc + (wn + ni * 16 + (lane & 15)) * 32 + (lane >> 4) * 8);
#pragma unroll
    for (int mi = 0; mi < 4; ++mi)
#pragma unroll
      for (int ni = 0; ni < 4; ++ni)
        acc[mi][ni] = __builtin_amdgcn_mfma_f32_16x16x32_bf16(af[mi], bg[ni], acc[mi][ni], 0, 0, 0);
  };

  STAGE(0, As0, Bs0);
  __syncthreads();  // covers qsh + prologue stage
  for (int f0 = 0; f0 < Fn; f0 += 64) {
    if (f0 + 32 < Fn) STAGE(f0 + 32, As1, Bs1);
    COMPUTE(As0, Bs0);
    __syncthreads();
    if (f0 + 64 < Fn) STAGE(f0 + 64, As0, Bs0);
    COMPUTE(As1, Bs1);
    __syncthreads();
  }

  float bias[4];
  const float* bptr = (kv ? bv : bk) + h * Dn;
#pragma unroll
  for (int ni = 0; ni < 4; ++ni) bias[ni] = bptr[wn + ni * 16 + (lane & 15)];
#pragma unroll
  for (int mi = 0; mi < 4; ++mi)
#pragma unroll
    for (int ni = 0; ni < 4; ++ni)
#pragma unroll
      for (int r = 0; r < 4; ++r) {
        int row = wm + mi * 16 + (lane >> 4) * 4 + r;  // t-local
        int col = wn + ni * 16 + (lane & 15);          // d
        float v = acc[mi][ni][r] + bias[ni];
        if (t0 + row >= Tn) v = 0.f;                   // zero-pad rows (Gram-safe)
        Cst[row * 130 + col] = f2bf(v);
      }
  __syncthreads();
  int d = tid >> 1, half = tid & 1;
  u16* orow = mhT + (((size_t)(kv * Bn + b) * Hn + h) * Dn + d) * TPn + t0;
  float ssum = 0.f, ssq = 0.f;
#pragma unroll
  for (int j = 0; j < 8; ++j) {
    int tb = half * 64 + j * 8;
    u16 pk[8];
#pragma unroll
    for (int ii = 0; ii < 8; ++ii) {
      u16 ub = Cst[(tb + ii) * 130 + d];
      pk[ii] = ub;
      float vr = bf2f(ub);
      ssum += vr;
      ssq += vr * vr;
    }
    uint4 v4;
    v4.x = (unsigned)pk[0] | ((unsigned)pk[1] << 16);
    v4.y = (unsigned)pk[2] | ((unsigned)pk[3] << 16);
    v4.z = (unsigned)pk[4] | ((unsigned)pk[5] << 16);
    v4.w = (unsigned)pk[6] | ((unsigned)pk[7] << 16);
    *reinterpret_cast<uint4*>(orow + tb) = v4;
  }
  int sidx = ((kv * Bn + b) * Hn + h) * Dn + d;
  atomicAdd(&s1buf[sidx], ssum);
  atomicAdd(&s2buf[sidx], ssq);

  // ---- fused attention scores (kv==0 only): s[t] = q . K[t,:]
  if (kv == 0) {
    int t = tid >> 1, hf = tid & 1;
    float s = 0.f;
    const u16* crow = Cst + t * 130 + hf * 64;
    const float* qh = qsh + hf * 64;
#pragma unroll
    for (int dd = 0; dd < 64; ++dd) s += qh[dd] * bf2f(crow[dd]);
    s += __shfl_xor(s, 1);
    if (hf == 0)
      scores[((size_t)b * Hn + h) * TPn + t0 + t] =
          (t0 + t < Tn) ? s * 0.088388347648318447f : -1e30f;
  }
}

// ---------------------------------------------------------------- k3b: softmax + PV (d-split x4)
__global__ __launch_bounds__(256) void k3b_pv(
    const u16* __restrict__ mhT, const float* __restrict__ scores,
    float* __restrict__ o1) {
  __shared__ float sc[TPn];
  __shared__ float red[256];
  int tid = threadIdx.x;
  int bh = blockIdx.x >> 2, dq = blockIdx.x & 3;
  int b = bh >> 3, h = bh & 7;
  const float* srow = scores + (size_t)bh * TPn;
  float4 z4 = *((const float4*)srow + tid);
  float z[4] = {z4.x, z4.y, z4.z, z4.w};
  float m = fmaxf(fmaxf(z[0], z[1]), fmaxf(z[2], z[3]));
  red[tid] = m;
  __syncthreads();
  for (int s = 128; s > 0; s >>= 1) { if (tid < s) red[tid] = fmaxf(red[tid], red[tid + s]); __syncthreads(); }
  m = red[0];
  __syncthreads();
  float lsum = 0.f;
#pragma unroll
  for (int j = 0; j < 4; ++j) {
    float e = __expf(z[j] - m);   // padded t wrote -1e30 -> e==0
    sc[tid * 4 + j] = e;
    lsum += e;
  }
  red[tid] = lsum;
  __syncthreads();
  for (int s = 128; s > 0; s >>= 1) { if (tid < s) red[tid] += red[tid + s]; __syncthreads(); }
  float inv = 1.f / red[0];
  // PV: lane dl handles d = dq*32+dl over t-slice of 128
  int dl = tid & 31, slice = tid >> 5;
  int d = dq * 32 + dl;
  const u16* Vr = mhT + ((size_t)(1 * Bn + b) * Hn + h) * Dn * TPn + (size_t)d * TPn + slice * 128;
  const float* at = sc + slice * 128;
  float a = 0.f;
#pragma unroll
  for (int i = 0; i < 16; ++i) {
    bf16x8 vv = *(const bf16x8*)(Vr + i * 8);
#pragma unroll
    for (int j = 0; j < 8; ++j) a += at[i * 8 + j] * (float)vv[j];
  }
  __syncthreads();  // everyone has read red[0] before re-use
  red[tid] = a;
  __syncthreads();
  for (int s = 128; s >= 32; s >>= 1) { if (tid < s) red[tid] += red[tid + s]; __syncthreads(); }
  if (tid < 32) o1[((size_t)b * Hn + h) * Dn + dq * 32 + tid] = inv * red[tid];
}

// ---------------------------------------------------------------- k4a: Gram partials (t-split x4)
// block = (bh, tc): Gram of K[.,tc*256..+256) x V over 8 BK=32 steps, dbuf.
__global__ __launch_bounds__(256) void k4a_gram(
    const u16* __restrict__ mhT, float* __restrict__ Sgp) {
  __shared__ __align__(16) u16 As0[4096], Bs0[4096], As1[4096], Bs1[4096];  // [128 d][32 t] each
  int tid = threadIdx.x, lane = tid & 63, w = tid >> 6;
  int bh = blockIdx.x, tc = blockIdx.y;
  int b = bh >> 3, h = bh & 7;
  const u16* Kb = mhT + ((size_t)(0 * Bn + b) * Hn + h) * Dn * TPn;
  const u16* Vb = mhT + ((size_t)(1 * Bn + b) * Hn + h) * Dn * TPn;
  f32x4 acc[4][4];
#pragma unroll
  for (int mi = 0; mi < 4; ++mi)
#pragma unroll
    for (int ni = 0; ni < 4; ++ni) acc[mi][ni] = (f32x4){0.f, 0.f, 0.f, 0.f};
  int wm = (w >> 1) * 64, wn = (w & 1) * 64;
  int lin0 = tid, lin1 = tid + 256;
  int row0 = lin0 >> 2, part0 = lin0 & 3;
  int row1 = lin1 >> 2, part1 = lin1 & 3;
  int wb0 = (w * 64) * 8, wb1 = (256 + w * 64) * 8;
  int tb = tc * 256;

  auto STAGE = [&](int t0, u16* Ad, u16* Bd) {
    gload_lds16(Kb + (size_t)row0 * TPn + t0 + part0 * 8, Ad + wb0);
    gload_lds16(Kb + (size_t)row1 * TPn + t0 + part1 * 8, Ad + wb1);
    gload_lds16(Vb + (size_t)row0 * TPn + t0 + part0 * 8, Bd + wb0);
    gload_lds16(Vb + (size_t)row1 * TPn + t0 + part1 * 8, Bd + wb1);
  };
  auto COMPUTE = [&](const u16* Ac, const u16* Bc) {
    bf16x8 af[4], bg[4];
#pragma unroll
    for (int mi = 0; mi < 4; ++mi)
      af[mi] = *(const bf16x8*)(Ac + (wm + mi * 16 + (lane & 15)) * 32 + (lane >> 4) * 8);
#pragma unroll
    for (int ni = 0; ni < 4; ++ni)
      bg[ni] = *(const bf16x8*)(Bc + (wn + ni * 16 + (lane & 15)) * 32 + (lane >> 4) * 8);
#pragma unroll
    for (int mi = 0; mi < 4; ++mi)
#pragma unroll
      for (int ni = 0; ni < 4; ++ni)
        acc[mi][ni] = __builtin_amdgcn_mfma_f32_16x16x32_bf16(af[mi], bg[ni], acc[mi][ni], 0, 0, 0);
  };

  STAGE(tb, As0, Bs0);
  __syncthreads();
  for (int s = 0; s < 256; s += 64) {
    if (s + 32 < 256) STAGE(tb + s + 32, As1, Bs1);
    COMPUTE(As0, Bs0);
    __syncthreads();
    if (s + 64 < 256) STAGE(tb + s + 64, As0, Bs0);
    COMPUTE(As1, Bs1);
    __syncthreads();
  }
  float* dst = Sgp + ((size_t)tc * 64 + bh) * 16384;
#pragma unroll
  for (int mi = 0; mi < 4; ++mi)
#pragma unroll
    for (int ni = 0; ni < 4; ++ni)
#pragma unroll
      for (int r = 0; r < 4; ++r) {
        int mm = wm + mi * 16 + (lane >> 4) * 4 + r;
        int nn = wn + ni * 16 + (lane & 15);
        dst[mm * 128 + nn] = acc[mi][ni][r];
      }
}

// ---------------------------------------------------------------- k4b: corr normalize
// block = (bh, quad): cells mm in [quad*32, +32), nn in [0,128)
__global__ __launch_bounds__(256) void k4b_corr(
    const float* __restrict__ Sgp, const float* __restrict__ s1buf,
    const float* __restrict__ s2buf, float* __restrict__ corr) {
  __shared__ float mkS[32], skS[32], mvS[128], svS[128];
  int tid = threadIdx.x;
  int bh = blockIdx.x >> 2, quad = blockIdx.x & 3;
  int b = bh >> 3, h = bh & 7;
  if (tid < 32) {
    int dd = quad * 32 + tid;
    int sidx = ((0 * Bn + b) * Hn + h) * Dn + dd;
    float a1 = s1buf[sidx], a2 = s2buf[sidx];
    float mu = a1 / (float)Tn;
    float var = (a2 - a1 * a1 / (float)Tn) / (float)(Tn - 1);
    mkS[tid] = mu;
    skS[tid] = sqrtf(fmaxf(var, 0.f)) + 1e-9f;
  } else if (tid < 160) {
    int dd = tid - 32;
    int sidx = ((1 * Bn + b) * Hn + h) * Dn + dd;
    float a1 = s1buf[sidx], a2 = s2buf[sidx];
    float mu = a1 / (float)Tn;
    float var = (a2 - a1 * a1 / (float)Tn) / (float)(Tn - 1);
    mvS[dd] = mu;
    svS[dd] = sqrtf(fmaxf(var, 0.f)) + 1e-9f;
  }
  __syncthreads();
  const float invT = 1.f / (float)Tn;
#pragma unroll
  for (int it = 0; it < 16; ++it) {
    int cell = it * 256 + tid;
    int ml = cell >> 7, nn = cell & 127;
    int mm = quad * 32 + ml;
    if (nn > mm) {
      size_t off = (size_t)bh * 16384 + mm * 128 + nn;
      float S = Sgp[off] + Sgp[off + (size_t)64 * 16384] +
                Sgp[off + (size_t)128 * 16384] + Sgp[off + (size_t)192 * 16384];
      float cv = (S - (float)Tn * mkS[ml] * mvS[nn]) * invT / (skS[ml] * svS[nn]);
      int cidx = mm * (2 * Dn - mm - 1) / 2 + (nn - mm - 1);
      corr[(size_t)bh * NCOR + cidx] = cv;
    }
  }
}

// ---------------------------------------------------------------- k5a: head proj
__global__ __launch_bounds__(256) void k5_proj(
    const float* __restrict__ corr, const float* __restrict__ Wproj,
    const float* __restrict__ bproj, float* __restrict__ outs) {
  __shared__ float red[8 * 256];
  int tid = threadIdx.x;
  int e = blockIdx.x, h = blockIdx.y;
  const float4* wp4 = (const float4*)(Wproj + ((size_t)h * En + e) * NCOR);
  float accs[8];
#pragma unroll
  for (int b = 0; b < 8; ++b) accs[b] = 0.f;
  for (int k = 0; k < 8; ++k) {
    int c4 = tid + k * 256;
    if (c4 < NCOR / 4) {
      float4 wv = wp4[c4];
#pragma unroll
      for (int b = 0; b < 8; ++b) {
        float4 cv = *((const float4*)(corr + ((size_t)b * Hn + h) * NCOR) + c4);
        accs[b] += wv.x * cv.x + wv.y * cv.y + wv.z * cv.z + wv.w * cv.w;
      }
    }
  }
#pragma unroll
  for (int b = 0; b < 8; ++b) red[b * 256 + tid] = accs[b];
  __syncthreads();
  for (int s = 128; s > 0; s >>= 1) {
    if (tid < s) {
#pragma unroll
      for (int b = 0; b < 8; ++b) red[b * 256 + tid] += red[b * 256 + tid + s];
    }
    __syncthreads();
  }
  if (tid < 8) outs[((size_t)tid * Hn + h) * En + e] = red[tid * 256] + bproj[h * En + e];
}

// ---------------------------------------------------------------- k5b: final mix
__global__ __launch_bounds__(256) void k5_final(
    const float* __restrict__ outs, const float* __restrict__ o1,
    const float* __restrict__ WT, const float* __restrict__ bT,
    const float* __restrict__ Wp, const float* __restrict__ bp,
    float* __restrict__ out) {
  __shared__ float os[2048];
  __shared__ float o1s[1024];
  __shared__ float redF[256], redT[256];
  int tid = threadIdx.x;
  int b = blockIdx.x >> 3, ic = blockIdx.x & 7;
  for (int i = tid; i < 2048; i += 256) os[i] = outs[(size_t)b * 2048 + i];
  for (int i = tid; i < 1024; i += 256) o1s[i] = o1[(size_t)b * 1024 + i];
  __syncthreads();
  int il = tid >> 3, slice = tid & 7;
  int i = ic * 32 + il;
  const float* wpr = Wp + (size_t)i * 2048;
  const float* wtr = WT + (size_t)i * 1024;
  float aF = 0.f, aT = 0.f;
  for (int kk = 0; kk < 256; ++kk) { int j = kk * 8 + slice; aF += os[j] * wpr[j]; }
  for (int kk = 0; kk < 128; ++kk) { int j = kk * 8 + slice; aT += o1s[j] * wtr[j]; }
  redF[tid] = aF; redT[tid] = aT;
  __syncthreads();
  for (int s = 4; s > 0; s >>= 1) {
    if (slice < s) { redF[tid] += redF[tid + s]; redT[tid] += redT[tid + s]; }
    __syncthreads();
  }
  if (slice == 0) {
    float oF = redF[tid] + bp[i];
    float oT = redT[tid] + bT[i];
    out[(size_t)b * En + i] = 0.5f * oF + 0.5f * oT;
  }
}

// ---------------------------------------------------------------- launch
extern "C" void kernel_launch(void* const* d_in, const int* in_sizes, int n_in,
                              void* d_out, int out_size, void* d_ws, size_t ws_size,
                              hipStream_t stream) {
  const float* x     = (const float*)d_in[0];
  const float* wk    = (const float*)d_in[1];
  const float* wv    = (const float*)d_in[2];
  const float* q     = (const float*)d_in[3];
  const float* Wk    = (const float*)d_in[4];
  const float* bk    = (const float*)d_in[5];
  const float* Wv    = (const float*)d_in[6];
  const float* bv    = (const float*)d_in[7];
  const float* Wproj = (const float*)d_in[8];
  const float* bproj = (const float*)d_in[9];
  const float* WT    = (const float*)d_in[10];
  const float* bT    = (const float*)d_in[11];
  const float* Wp    = (const float*)d_in[12];
  const float* bp    = (const float*)d_in[13];
  float* out = (float*)d_out;

  char* ws = (char*)d_ws;
  size_t off = 0;
  auto alloc = [&](size_t bytes) { size_t p = off; off += (bytes + 255) & ~(size_t)255; return p; };
  float* kvw    = (float*)(ws + alloc((size_t)2 * Hn * Ln * 4));
  u16*   Wbf    = (u16*)  (ws + alloc((size_t)2 * Hn * Dn * Fn * 2));
  u16*   mhT    = (u16*)  (ws + alloc((size_t)2 * Bn * Hn * Dn * TPn * 2));
  float* s1     = (float*)(ws + alloc((size_t)2 * Bn * Hn * Dn * 4));
  float* s2     = (float*)(ws + alloc((size_t)2 * Bn * Hn * Dn * 4));
  float* o1     = (float*)(ws + alloc((size_t)Bn * Hn * Dn * 4));
  float* corr   = (float*)(ws + alloc((size_t)Bn * Hn * NCOR * 4));
  float* outs   = (float*)(ws + alloc((size_t)Bn * Hn * En * 4));
  float* scores = (float*)(ws + alloc((size_t)Bn * Hn * TPn * 4));
  float* Sgp    = (float*)(ws + alloc((size_t)4 * Bn * Hn * Dn * Dn * 4));  // 16.8 MB
  size_t fixed = off;
  size_t per_b = (size_t)2 * Hn * TPn * Fn * 2;  // kv_raw per batch: 24 MB
  int BG = 8;
  while (BG > 1 && fixed + (size_t)BG * per_b > ws_size) BG >>= 1;
  u16* kv_raw = (u16*)(ws + fixed);

  k0_prep<<<6144, 256, 0, stream>>>(wk, wv, Wk, Wv, kvw, Wbf, s1, s2);
  for (int b0 = 0; b0 < Bn; b0 += BG) {
    k1_raw<<<dim3(24, 32, BG), 256, 0, stream>>>(x, kvw, kv_raw, b0, BG);
    k2_gemm<<<dim3(8, Hn * BG, 2), 256, 0, stream>>>(kv_raw, Wbf, bk, bv, q, mhT, s1, s2,
                                                     scores, b0, BG);
  }
  k3b_pv<<<256, 256, 0, stream>>>(mhT, scores, o1);
  k4a_gram<<<dim3(64, 4), 256, 0, stream>>>(mhT, Sgp);
  k4b_corr<<<256, 256, 0, stream>>>(Sgp, s1, s2, corr);
  k5_proj<<<dim3(En, Hn), 256, 0, stream>>>(corr, Wproj, bproj, outs);
  k5_final<<<64, 256, 0, stream>>>(outs, o1, WT, bT, Wp, bp, out);
}

// Round 2
// 669.770 us; speedup vs baseline: 1.0486x; 1.0168x over previous
//
#include <hip/hip_runtime.h>
#include <hip/hip_bf16.h>

#define Hn 8
#define Fn 768
#define Dn 128
#define En 256
#define Ln 13
#define Bn 8
#define Tn 1000
#define TPn 1024
#define NCOR 8128

typedef float f32x4 __attribute__((ext_vector_type(4)));
typedef __bf16 bf16x8 __attribute__((ext_vector_type(8)));
typedef unsigned short u16;

static __device__ __forceinline__ u16 f2bf(float f) {
  __hip_bfloat16 h = __float2bfloat16(f);
  return __builtin_bit_cast(u16, h);
}
static __device__ __forceinline__ float bf2f(u16 u) {
  return __bfloat162float(__builtin_bit_cast(__hip_bfloat16, u));
}

// async global->LDS, 16B per lane. LDS dest must be wave-uniform base; HW adds lane*16.
static __device__ __forceinline__ void gload_lds16(const u16* g, u16* lds_wave_base) {
  __builtin_amdgcn_global_load_lds(
      (const __attribute__((address_space(1))) unsigned int*)g,
      (__attribute__((address_space(3))) unsigned int*)lds_wave_base, 16, 0, 0);
}

// ---------------------------------------------------------------- k1: l-reduce (+folded prep)
// thread = (f-lane 0..31, t-quad 0..7): 13 float4 loads cover 4 consecutive t.
// res LDS [o][t][f+pad2] transpose; phase C: 4 lanes assemble one 64B row.
// Folded former k0: per-block kvw softmax (cheap, deterministic) + grid-spread
// Wbf f32->bf16 conversion + s1/s2 zeroing (b0==0 only; completes before k2 launch).
__global__ __launch_bounds__(256) void k1_raw(
    const float* __restrict__ x,
    const float* __restrict__ wk, const float* __restrict__ wv,
    const float* __restrict__ Wk, const float* __restrict__ Wv,
    u16* __restrict__ kv_raw, u16* __restrict__ Wbf,
    float* __restrict__ s1, float* __restrict__ s2,
    int b0, int BG) {
  __shared__ float kvw[16 * Ln];
  __shared__ u16 res[16 * 32 * 34];  // 34816 B; row stride 34 (17 uints, odd)
  int tid = threadIdx.x;
  if (tid < 16) {
    int kvi = tid >> 3, h = tid & 7;
    const float* w = (kvi ? wv : wk) + h * Ln;
    float m = -1e30f;
    for (int l = 0; l < Ln; ++l) m = fmaxf(m, w[l]);
    float e[Ln], s = 0.f;
    for (int l = 0; l < Ln; ++l) { e[l] = expf(w[l] - m); s += e[l]; }
    for (int l = 0; l < Ln; ++l) kvw[tid * Ln + l] = e[l] / s;
  }
  if (b0 == 0) {  // folded k0 work; only the first batch-group pass
    int nb = gridDim.x * gridDim.y * gridDim.z;
    int lin = blockIdx.x + gridDim.x * (blockIdx.y + gridDim.y * blockIdx.z);
    int n = 2 * Hn * Dn * Fn;  // 1572864 == 6144*256: one elem/thread at BG=8
    for (int i = lin * 256 + tid; i < n; i += nb * 256) {
      float v = (i < Hn * Dn * Fn) ? Wk[i] : Wv[i - Hn * Dn * Fn];
      Wbf[i] = f2bf(v);
    }
    int ns = 2 * Bn * Hn * Dn;
    for (int i = lin * 256 + tid; i < ns; i += nb * 256) { s1[i] = 0.f; s2[i] = 0.f; }
  }
  int f0 = blockIdx.x * 32, t0 = blockIdx.y * 32;
  int b_l = blockIdx.z, b = b0 + b_l;
  int fl = tid & 31, tq = tid >> 5;
  int tbase = t0 + tq * 4;
  bool valid = (tbase < Tn);  // Tn%4==0 -> quads never straddle
  float4 xq[13];
  if (valid) {
    const float4* xp = (const float4*)(x + ((size_t)(b * Fn + f0 + fl) * Tn + tbase) * Ln);
#pragma unroll
    for (int i = 0; i < 13; ++i) xq[i] = xp[i];
  }
  __syncthreads();
  const float* xf = (const float*)xq;
  for (int o = 0; o < 16; ++o) {
    float a0 = 0.f, a1 = 0.f, a2 = 0.f, a3 = 0.f;
    if (valid) {
#pragma unroll
      for (int l = 0; l < Ln; ++l) {
        float w = kvw[o * Ln + l];
        a0 += xf[l] * w;
        a1 += xf[Ln + l] * w;
        a2 += xf[2 * Ln + l] * w;
        a3 += xf[3 * Ln + l] * w;
      }
    }
    int rb = o * 1088 + tq * 4 * 34 + fl;
    res[rb] = f2bf(a0);
    res[rb + 34] = f2bf(a1);
    res[rb + 68] = f2bf(a2);
    res[rb + 102] = f2bf(a3);
  }
  __syncthreads();
  int part = tid & 3;
#pragma unroll
  for (int it = 0; it < 8; ++it) {
    int r = (tid >> 2) + it * 64;
    int o = r >> 5, tl = r & 31;
    int kv = o >> 3, h = o & 7;
    const u16* src = res + o * 1088 + tl * 34 + part * 8;
    uint4 v;
    v.x = *(const unsigned*)(src + 0);
    v.y = *(const unsigned*)(src + 2);
    v.z = *(const unsigned*)(src + 4);
    v.w = *(const unsigned*)(src + 6);
    u16* dst = kv_raw + (((size_t)(kv * BG + b_l) * Hn + h) * TPn + t0 + tl) * Fn + f0 + part * 8;
    *reinterpret_cast<uint4*>(dst) = v;
  }
}

// ---------------------------------------------------------------- k2: main GEMM
// 128x128 tile, BK=32, bf16 MFMA. 2-phase double-buffered async staging
// (1 barrier per K-step). Fused: scores = q.K for kv==0 tiles.
__global__ __launch_bounds__(256) void k2_gemm(
    const u16* __restrict__ kv_raw, const u16* __restrict__ Wbf,
    const float* __restrict__ bk, const float* __restrict__ bv,
    const float* __restrict__ qg,
    u16* __restrict__ mhT, float* __restrict__ s1buf, float* __restrict__ s2buf,
    float* __restrict__ scores, int b0, int BG) {
  __shared__ __align__(16) char ldsbuf[33280];
  __shared__ float qsh[Dn];
  u16* As0 = (u16*)ldsbuf;             // [128 t][32 f]  8KB
  u16* Bs0 = (u16*)(ldsbuf + 8192);    // [128 d][32 f]  8KB
  u16* As1 = (u16*)(ldsbuf + 16384);
  u16* Bs1 = (u16*)(ldsbuf + 24576);
  u16* Cst = (u16*)ldsbuf;             // [128 t][130] (reused after K-loop)
  int tid = threadIdx.x, lane = tid & 63, w = tid >> 6;
  int t0 = blockIdx.x * 128;
  int b_l = blockIdx.y / Hn, h = blockIdx.y % Hn, kv = blockIdx.z;
  int b = b0 + b_l;
  if (tid < Dn) qsh[tid] = qg[h * Dn + tid];
  const u16* Abase = kv_raw + ((size_t)(kv * BG + b_l) * Hn + h) * TPn * Fn + (size_t)t0 * Fn;
  const u16* Bbase = Wbf + ((size_t)(kv * Hn + h)) * Dn * Fn;
  f32x4 acc[4][4];
#pragma unroll
  for (int mi = 0; mi < 4; ++mi)
#pragma unroll
    for (int ni = 0; ni < 4; ++ni) acc[mi][ni] = (f32x4){0.f, 0.f, 0.f, 0.f};
  int wm = (w >> 1) * 64, wn = (w & 1) * 64;
  int lin0 = tid, lin1 = tid + 256;
  int row0 = lin0 >> 2, part0 = lin0 & 3;
  int row1 = lin1 >> 2, part1 = lin1 & 3;
  int wb0 = (w * 64) * 8, wb1 = (256 + w * 64) * 8;  // wave-uniform LDS elem base

  auto STAGE = [&](int f0, u16* Ad, u16* Bd) {
    gload_lds16(Abase + (size_t)row0 * Fn + f0 + part0 * 8, Ad + wb0);
    gload_lds16(Abase + (size_t)row1 * Fn + f0 + part1 * 8, Ad + wb1);
    gload_lds16(Bbase + (size_t)row0 * Fn + f0 + part0 * 8, Bd + wb0);
    gload_lds16(Bbase + (size_t)row1 * Fn + f0 + part1 * 8, Bd + wb1);
  };
  auto COMPUTE = [&](const u16* Ac, const u16* Bc) {
    bf16x8 af[4], bg[4];
#pragma unroll
    for (int mi = 0; mi < 4; ++mi)
      af[mi] = *(const bf16x8*)(Ac + (wm + mi * 16 + (lane & 15)) * 32 + (lane >> 4) * 8);
#pragma unroll
    for (int ni = 0; ni < 4; ++ni)
      bg[ni] = *(const bf16x8*)(Bc + (wn + ni * 16 + (lane & 15)) * 32 + (lane >> 4) * 8);
#pragma unroll
    for (int mi = 0; mi < 4; ++mi)
#pragma unroll
      for (int ni = 0; ni < 4; ++ni)
        acc[mi][ni] = __builtin_amdgcn_mfma_f32_16x16x32_bf16(af[mi], bg[ni], acc[mi][ni], 0, 0, 0);
  };

  STAGE(0, As0, Bs0);
  __syncthreads();  // covers qsh + prologue stage
  for (int f0 = 0; f0 < Fn; f0 += 64) {
    if (f0 + 32 < Fn) STAGE(f0 + 32, As1, Bs1);
    COMPUTE(As0, Bs0);
    __syncthreads();
    if (f0 + 64 < Fn) STAGE(f0 + 64, As0, Bs0);
    COMPUTE(As1, Bs1);
    __syncthreads();
  }

  float bias[4];
  const float* bptr = (kv ? bv : bk) + h * Dn;
#pragma unroll
  for (int ni = 0; ni < 4; ++ni) bias[ni] = bptr[wn + ni * 16 + (lane & 15)];
#pragma unroll
  for (int mi = 0; mi < 4; ++mi)
#pragma unroll
    for (int ni = 0; ni < 4; ++ni)
#pragma unroll
      for (int r = 0; r < 4; ++r) {
        int row = wm + mi * 16 + (lane >> 4) * 4 + r;  // t-local
        int col = wn + ni * 16 + (lane & 15);          // d
        float v = acc[mi][ni][r] + bias[ni];
        if (t0 + row >= Tn) v = 0.f;                   // zero-pad rows (Gram-safe)
        Cst[row * 130 + col] = f2bf(v);
      }
  __syncthreads();
  int d = tid >> 1, half = tid & 1;
  u16* orow = mhT + (((size_t)(kv * Bn + b) * Hn + h) * Dn + d) * TPn + t0;
  float ssum = 0.f, ssq = 0.f;
#pragma unroll
  for (int j = 0; j < 8; ++j) {
    int tb = half * 64 + j * 8;
    u16 pk[8];
#pragma unroll
    for (int ii = 0; ii < 8; ++ii) {
      u16 ub = Cst[(tb + ii) * 130 + d];
      pk[ii] = ub;
      float vr = bf2f(ub);
      ssum += vr;
      ssq += vr * vr;
    }
    uint4 v4;
    v4.x = (unsigned)pk[0] | ((unsigned)pk[1] << 16);
    v4.y = (unsigned)pk[2] | ((unsigned)pk[3] << 16);
    v4.z = (unsigned)pk[4] | ((unsigned)pk[5] << 16);
    v4.w = (unsigned)pk[6] | ((unsigned)pk[7] << 16);
    *reinterpret_cast<uint4*>(orow + tb) = v4;
  }
  int sidx = ((kv * Bn + b) * Hn + h) * Dn + d;
  atomicAdd(&s1buf[sidx], ssum);
  atomicAdd(&s2buf[sidx], ssq);

  // ---- fused attention scores (kv==0 only): s[t] = q . K[t,:]
  if (kv == 0) {
    int t = tid >> 1, hf = tid & 1;
    float s = 0.f;
    const u16* crow = Cst + t * 130 + hf * 64;
    const float* qh = qsh + hf * 64;
#pragma unroll
    for (int dd = 0; dd < 64; ++dd) s += qh[dd] * bf2f(crow[dd]);
    s += __shfl_xor(s, 1);
    if (hf == 0)
      scores[((size_t)b * Hn + h) * TPn + t0 + t] =
          (t0 + t < Tn) ? s * 0.088388347648318447f : -1e30f;
  }
}

// ---------------------------------------------------------------- k34: merged PV + Gram
// blocks 0..255: softmax+PV (d-split x4). blocks 256..511: Gram partials (t-split x4).
__global__ __launch_bounds__(256) void k34(
    const u16* __restrict__ mhT, const float* __restrict__ scores,
    float* __restrict__ o1, float* __restrict__ Sgp) {
  __shared__ float sc[TPn];
  __shared__ float red[256];
  __shared__ __align__(16) u16 As0[4096], Bs0[4096], As1[4096], Bs1[4096];
  int tid = threadIdx.x;
  if (blockIdx.x < 256) {
    // ---------------- PV branch
    int bh = blockIdx.x >> 2, dq = blockIdx.x & 3;
    int b = bh >> 3, h = bh & 7;
    const float* srow = scores + (size_t)bh * TPn;
    float4 z4 = *((const float4*)srow + tid);
    float z[4] = {z4.x, z4.y, z4.z, z4.w};
    float m = fmaxf(fmaxf(z[0], z[1]), fmaxf(z[2], z[3]));
    red[tid] = m;
    __syncthreads();
    for (int s = 128; s > 0; s >>= 1) { if (tid < s) red[tid] = fmaxf(red[tid], red[tid + s]); __syncthreads(); }
    m = red[0];
    __syncthreads();
    float lsum = 0.f;
#pragma unroll
    for (int j = 0; j < 4; ++j) {
      float e = __expf(z[j] - m);   // padded t wrote -1e30 -> e==0
      sc[tid * 4 + j] = e;
      lsum += e;
    }
    red[tid] = lsum;
    __syncthreads();
    for (int s = 128; s > 0; s >>= 1) { if (tid < s) red[tid] += red[tid + s]; __syncthreads(); }
    float inv = 1.f / red[0];
    int dl = tid & 31, slice = tid >> 5;
    int d = dq * 32 + dl;
    const u16* Vr = mhT + ((size_t)(1 * Bn + b) * Hn + h) * Dn * TPn + (size_t)d * TPn + slice * 128;
    const float* at = sc + slice * 128;
    float a = 0.f;
#pragma unroll
    for (int i = 0; i < 16; ++i) {
      bf16x8 vv = *(const bf16x8*)(Vr + i * 8);
#pragma unroll
      for (int j = 0; j < 8; ++j) a += at[i * 8 + j] * (float)vv[j];
    }
    __syncthreads();
    red[tid] = a;
    __syncthreads();
    for (int s = 128; s >= 32; s >>= 1) { if (tid < s) red[tid] += red[tid + s]; __syncthreads(); }
    if (tid < 32) o1[((size_t)b * Hn + h) * Dn + dq * 32 + tid] = inv * red[tid];
    return;
  }
  // ---------------- Gram branch
  int id = blockIdx.x - 256;
  int lane = tid & 63, w = tid >> 6;
  int bh = id & 63, tc = id >> 6;
  int b = bh >> 3, h = bh & 7;
  const u16* Kb = mhT + ((size_t)(0 * Bn + b) * Hn + h) * Dn * TPn;
  const u16* Vb = mhT + ((size_t)(1 * Bn + b) * Hn + h) * Dn * TPn;
  f32x4 acc[4][4];
#pragma unroll
  for (int mi = 0; mi < 4; ++mi)
#pragma unroll
    for (int ni = 0; ni < 4; ++ni) acc[mi][ni] = (f32x4){0.f, 0.f, 0.f, 0.f};
  int wm = (w >> 1) * 64, wn = (w & 1) * 64;
  int lin0 = tid, lin1 = tid + 256;
  int row0 = lin0 >> 2, part0 = lin0 & 3;
  int row1 = lin1 >> 2, part1 = lin1 & 3;
  int wb0 = (w * 64) * 8, wb1 = (256 + w * 64) * 8;
  int tb = tc * 256;

  auto STAGE = [&](int t0, u16* Ad, u16* Bd) {
    gload_lds16(Kb + (size_t)row0 * TPn + t0 + part0 * 8, Ad + wb0);
    gload_lds16(Kb + (size_t)row1 * TPn + t0 + part1 * 8, Ad + wb1);
    gload_lds16(Vb + (size_t)row0 * TPn + t0 + part0 * 8, Bd + wb0);
    gload_lds16(Vb + (size_t)row1 * TPn + t0 + part1 * 8, Bd + wb1);
  };
  auto COMPUTE = [&](const u16* Ac, const u16* Bc) {
    bf16x8 af[4], bg[4];
#pragma unroll
    for (int mi = 0; mi < 4; ++mi)
      af[mi] = *(const bf16x8*)(Ac + (wm + mi * 16 + (lane & 15)) * 32 + (lane >> 4) * 8);
#pragma unroll
    for (int ni = 0; ni < 4; ++ni)
      bg[ni] = *(const bf16x8*)(Bc + (wn + ni * 16 + (lane & 15)) * 32 + (lane >> 4) * 8);
#pragma unroll
    for (int mi = 0; mi < 4; ++mi)
#pragma unroll
      for (int ni = 0; ni < 4; ++ni)
        acc[mi][ni] = __builtin_amdgcn_mfma_f32_16x16x32_bf16(af[mi], bg[ni], acc[mi][ni], 0, 0, 0);
  };

  STAGE(tb, As0, Bs0);
  __syncthreads();
  for (int s = 0; s < 256; s += 64) {
    if (s + 32 < 256) STAGE(tb + s + 32, As1, Bs1);
    COMPUTE(As0, Bs0);
    __syncthreads();
    if (s + 64 < 256) STAGE(tb + s + 64, As0, Bs0);
    COMPUTE(As1, Bs1);
    __syncthreads();
  }
  float* dst = Sgp + ((size_t)tc * 64 + bh) * 16384;
#pragma unroll
  for (int mi = 0; mi < 4; ++mi)
#pragma unroll
    for (int ni = 0; ni < 4; ++ni)
#pragma unroll
      for (int r = 0; r < 4; ++r) {
        int mm = wm + mi * 16 + (lane >> 4) * 4 + r;
        int nn = wn + ni * 16 + (lane & 15);
        dst[mm * 128 + nn] = acc[mi][ni][r];
      }
}

// ---------------------------------------------------------------- k4b: corr normalize
// block = (bh, quad): cells mm in [quad*32, +32), nn in [0,128)
__global__ __launch_bounds__(256) void k4b_corr(
    const float* __restrict__ Sgp, const float* __restrict__ s1buf,
    const float* __restrict__ s2buf, float* __restrict__ corr) {
  __shared__ float mkS[32], skS[32], mvS[128], svS[128];
  int tid = threadIdx.x;
  int bh = blockIdx.x >> 2, quad = blockIdx.x & 3;
  int b = bh >> 3, h = bh & 7;
  if (tid < 32) {
    int dd = quad * 32 + tid;
    int sidx = ((0 * Bn + b) * Hn + h) * Dn + dd;
    float a1 = s1buf[sidx], a2 = s2buf[sidx];
    float mu = a1 / (float)Tn;
    float var = (a2 - a1 * a1 / (float)Tn) / (float)(Tn - 1);
    mkS[tid] = mu;
    skS[tid] = sqrtf(fmaxf(var, 0.f)) + 1e-9f;
  } else if (tid < 160) {
    int dd = tid - 32;
    int sidx = ((1 * Bn + b) * Hn + h) * Dn + dd;
    float a1 = s1buf[sidx], a2 = s2buf[sidx];
    float mu = a1 / (float)Tn;
    float var = (a2 - a1 * a1 / (float)Tn) / (float)(Tn - 1);
    mvS[dd] = mu;
    svS[dd] = sqrtf(fmaxf(var, 0.f)) + 1e-9f;
  }
  __syncthreads();
  const float invT = 1.f / (float)Tn;
#pragma unroll
  for (int it = 0; it < 16; ++it) {
    int cell = it * 256 + tid;
    int ml = cell >> 7, nn = cell & 127;
    int mm = quad * 32 + ml;
    if (nn > mm) {
      size_t off = (size_t)bh * 16384 + mm * 128 + nn;
      float S = Sgp[off] + Sgp[off + (size_t)64 * 16384] +
                Sgp[off + (size_t)128 * 16384] + Sgp[off + (size_t)192 * 16384];
      float cv = (S - (float)Tn * mkS[ml] * mvS[nn]) * invT / (skS[ml] * svS[nn]);
      int cidx = mm * (2 * Dn - mm - 1) / 2 + (nn - mm - 1);
      corr[(size_t)bh * NCOR + cidx] = cv;
    }
  }
}

// ---------------------------------------------------------------- k5a: head proj
__global__ __launch_bounds__(256) void k5_proj(
    const float* __restrict__ corr, const float* __restrict__ Wproj,
    const float* __restrict__ bproj, float* __restrict__ outs) {
  __shared__ float red[8 * 256];
  int tid = threadIdx.x;
  int e = blockIdx.x, h = blockIdx.y;
  const float4* wp4 = (const float4*)(Wproj + ((size_t)h * En + e) * NCOR);
  float accs[8];
#pragma unroll
  for (int b = 0; b < 8; ++b) accs[b] = 0.f;
  for (int k = 0; k < 8; ++k) {
    int c4 = tid + k * 256;
    if (c4 < NCOR / 4) {
      float4 wv = wp4[c4];
#pragma unroll
      for (int b = 0; b < 8; ++b) {
        float4 cv = *((const float4*)(corr + ((size_t)b * Hn + h) * NCOR) + c4);
        accs[b] += wv.x * cv.x + wv.y * cv.y + wv.z * cv.z + wv.w * cv.w;
      }
    }
  }
#pragma unroll
  for (int b = 0; b < 8; ++b) red[b * 256 + tid] = accs[b];
  __syncthreads();
  for (int s = 128; s > 0; s >>= 1) {
    if (tid < s) {
#pragma unroll
      for (int b = 0; b < 8; ++b) red[b * 256 + tid] += red[b * 256 + tid + s];
    }
    __syncthreads();
  }
  if (tid < 8) outs[((size_t)tid * Hn + h) * En + e] = red[tid * 256] + bproj[h * En + e];
}

// ---------------------------------------------------------------- k5b: final mix
__global__ __launch_bounds__(256) void k5_final(
    const float* __restrict__ outs, const float* __restrict__ o1,
    const float* __restrict__ WT, const float* __restrict__ bT,
    const float* __restrict__ Wp, const float* __restrict__ bp,
    float* __restrict__ out) {
  __shared__ float os[2048];
  __shared__ float o1s[1024];
  __shared__ float redF[256], redT[256];
  int tid = threadIdx.x;
  int b = blockIdx.x >> 3, ic = blockIdx.x & 7;
  for (int i = tid; i < 2048; i += 256) os[i] = outs[(size_t)b * 2048 + i];
  for (int i = tid; i < 1024; i += 256) o1s[i] = o1[(size_t)b * 1024 + i];
  __syncthreads();
  int il = tid >> 3, slice = tid & 7;
  int i = ic * 32 + il;
  const float* wpr = Wp + (size_t)i * 2048;
  const float* wtr = WT + (size_t)i * 1024;
  float aF = 0.f, aT = 0.f;
  for (int kk = 0; kk < 256; ++kk) { int j = kk * 8 + slice; aF += os[j] * wpr[j]; }
  for (int kk = 0; kk < 128; ++kk) { int j = kk * 8 + slice; aT += o1s[j] * wtr[j]; }
  redF[tid] = aF; redT[tid] = aT;
  __syncthreads();
  for (int s = 4; s > 0; s >>= 1) {
    if (slice < s) { redF[tid] += redF[tid + s]; redT[tid] += redT[tid + s]; }
    __syncthreads();
  }
  if (slice == 0) {
    float oF = redF[tid] + bp[i];
    float oT = redT[tid] + bT[i];
    out[(size_t)b * En + i] = 0.5f * oF + 0.5f * oT;
  }
}

// ---------------------------------------------------------------- launch
extern "C" void kernel_launch(void* const* d_in, const int* in_sizes, int n_in,
                              void* d_out, int out_size, void* d_ws, size_t ws_size,
                              hipStream_t stream) {
  const float* x     = (const float*)d_in[0];
  const float* wk    = (const float*)d_in[1];
  const float* wv    = (const float*)d_in[2];
  const float* q     = (const float*)d_in[3];
  const float* Wk    = (const float*)d_in[4];
  const float* bk    = (const float*)d_in[5];
  const float* Wv    = (const float*)d_in[6];
  const float* bv    = (const float*)d_in[7];
  const float* Wproj = (const float*)d_in[8];
  const float* bproj = (const float*)d_in[9];
  const float* WT    = (const float*)d_in[10];
  const float* bT    = (const float*)d_in[11];
  const float* Wp    = (const float*)d_in[12];
  const float* bp    = (const float*)d_in[13];
  float* out = (float*)d_out;

  char* ws = (char*)d_ws;
  size_t off = 0;
  auto alloc = [&](size_t bytes) { size_t p = off; off += (bytes + 255) & ~(size_t)255; return p; };
  u16*   Wbf    = (u16*)  (ws + alloc((size_t)2 * Hn * Dn * Fn * 2));
  u16*   mhT    = (u16*)  (ws + alloc((size_t)2 * Bn * Hn * Dn * TPn * 2));
  float* s1     = (float*)(ws + alloc((size_t)2 * Bn * Hn * Dn * 4));
  float* s2     = (float*)(ws + alloc((size_t)2 * Bn * Hn * Dn * 4));
  float* o1     = (float*)(ws + alloc((size_t)Bn * Hn * Dn * 4));
  float* corr   = (float*)(ws + alloc((size_t)Bn * Hn * NCOR * 4));
  float* outs   = (float*)(ws + alloc((size_t)Bn * Hn * En * 4));
  float* scores = (float*)(ws + alloc((size_t)Bn * Hn * TPn * 4));
  float* Sgp    = (float*)(ws + alloc((size_t)4 * Bn * Hn * Dn * Dn * 4));  // 16.8 MB
  size_t fixed = off;
  size_t per_b = (size_t)2 * Hn * TPn * Fn * 2;  // kv_raw per batch: 24 MB
  int BG = 8;
  while (BG > 1 && fixed + (size_t)BG * per_b > ws_size) BG >>= 1;
  u16* kv_raw = (u16*)(ws + fixed);

  for (int b0 = 0; b0 < Bn; b0 += BG) {
    k1_raw<<<dim3(24, 32, BG), 256, 0, stream>>>(x, wk, wv, Wk, Wv, kv_raw, Wbf, s1, s2, b0, BG);
    k2_gemm<<<dim3(8, Hn * BG, 2), 256, 0, stream>>>(kv_raw, Wbf, bk, bv, q, mhT, s1, s2,
                                                     scores, b0, BG);
  }
  k34<<<512, 256, 0, stream>>>(mhT, scores, o1, Sgp);
  k4b_corr<<<256, 256, 0, stream>>>(Sgp, s1, s2, corr);
  k5_proj<<<dim3(En, Hn), 256, 0, stream>>>(corr, Wproj, bproj, outs);
  k5_final<<<64, 256, 0, stream>>>(outs, o1, WT, bT, Wp, bp, out);
}

// Round 3
// 667.979 us; speedup vs baseline: 1.0514x; 1.0027x over previous
//
#include <hip/hip_runtime.h>
#include <hip/hip_bf16.h>

#define Hn 8
#define Fn 768
#define Dn 128
#define En 256
#define Ln 13
#define Bn 8
#define Tn 1000
#define TPn 1024
#define NCOR 8128

typedef float f32x4 __attribute__((ext_vector_type(4)));
typedef __bf16 bf16x8 __attribute__((ext_vector_type(8)));
typedef unsigned short u16;

static __device__ __forceinline__ u16 f2bf(float f) {
  __hip_bfloat16 h = __float2bfloat16(f);
  return __builtin_bit_cast(u16, h);
}
static __device__ __forceinline__ float bf2f(u16 u) {
  return __bfloat162float(__builtin_bit_cast(__hip_bfloat16, u));
}

// async global->LDS, 16B per lane. LDS dest must be wave-uniform base; HW adds lane*16.
static __device__ __forceinline__ void gload_lds16(const u16* g, u16* lds_wave_base) {
  __builtin_amdgcn_global_load_lds(
      (const __attribute__((address_space(1))) unsigned int*)g,
      (__attribute__((address_space(3))) unsigned int*)lds_wave_base, 16, 0, 0);
}

// ---------------------------------------------------------------- k1: l-reduce (+folded prep)
__global__ __launch_bounds__(256) void k1_raw(
    const float* __restrict__ x,
    const float* __restrict__ wk, const float* __restrict__ wv,
    const float* __restrict__ Wk, const float* __restrict__ Wv,
    u16* __restrict__ kv_raw, u16* __restrict__ Wbf,
    float* __restrict__ s1, float* __restrict__ s2,
    int b0, int BG) {
  __shared__ float kvw[16 * Ln];
  __shared__ u16 res[16 * 32 * 34];  // 34816 B; row stride 34 (17 uints, odd)
  int tid = threadIdx.x;
  if (tid < 16) {
    int kvi = tid >> 3, h = tid & 7;
    const float* w = (kvi ? wv : wk) + h * Ln;
    float m = -1e30f;
    for (int l = 0; l < Ln; ++l) m = fmaxf(m, w[l]);
    float e[Ln], s = 0.f;
    for (int l = 0; l < Ln; ++l) { e[l] = expf(w[l] - m); s += e[l]; }
    for (int l = 0; l < Ln; ++l) kvw[tid * Ln + l] = e[l] / s;
  }
  if (b0 == 0) {  // folded k0 work; only the first batch-group pass
    int nb = gridDim.x * gridDim.y * gridDim.z;
    int lin = blockIdx.x + gridDim.x * (blockIdx.y + gridDim.y * blockIdx.z);
    int n = 2 * Hn * Dn * Fn;  // 1572864 == 6144*256: one elem/thread at BG=8
    for (int i = lin * 256 + tid; i < n; i += nb * 256) {
      float v = (i < Hn * Dn * Fn) ? Wk[i] : Wv[i - Hn * Dn * Fn];
      Wbf[i] = f2bf(v);
    }
    int ns = 2 * Bn * Hn * Dn;
    for (int i = lin * 256 + tid; i < ns; i += nb * 256) { s1[i] = 0.f; s2[i] = 0.f; }
  }
  int f0 = blockIdx.x * 32, t0 = blockIdx.y * 32;
  int b_l = blockIdx.z, b = b0 + b_l;
  int fl = tid & 31, tq = tid >> 5;
  int tbase = t0 + tq * 4;
  bool valid = (tbase < Tn);  // Tn%4==0 -> quads never straddle
  float4 xq[13];
  if (valid) {
    const float4* xp = (const float4*)(x + ((size_t)(b * Fn + f0 + fl) * Tn + tbase) * Ln);
#pragma unroll
    for (int i = 0; i < 13; ++i) xq[i] = xp[i];
  }
  __syncthreads();
  const float* xf = (const float*)xq;
  for (int o = 0; o < 16; ++o) {
    float a0 = 0.f, a1 = 0.f, a2 = 0.f, a3 = 0.f;
    if (valid) {
#pragma unroll
      for (int l = 0; l < Ln; ++l) {
        float w = kvw[o * Ln + l];
        a0 += xf[l] * w;
        a1 += xf[Ln + l] * w;
        a2 += xf[2 * Ln + l] * w;
        a3 += xf[3 * Ln + l] * w;
      }
    }
    int rb = o * 1088 + tq * 4 * 34 + fl;
    res[rb] = f2bf(a0);
    res[rb + 34] = f2bf(a1);
    res[rb + 68] = f2bf(a2);
    res[rb + 102] = f2bf(a3);
  }
  __syncthreads();
  int part = tid & 3;
#pragma unroll
  for (int it = 0; it < 8; ++it) {
    int r = (tid >> 2) + it * 64;
    int o = r >> 5, tl = r & 31;
    int kv = o >> 3, h = o & 7;
    const u16* src = res + o * 1088 + tl * 34 + part * 8;
    uint4 v;
    v.x = *(const unsigned*)(src + 0);
    v.y = *(const unsigned*)(src + 2);
    v.z = *(const unsigned*)(src + 4);
    v.w = *(const unsigned*)(src + 6);
    u16* dst = kv_raw + (((size_t)(kv * BG + b_l) * Hn + h) * TPn + t0 + tl) * Fn + f0 + part * 8;
    *reinterpret_cast<uint4*>(dst) = v;
  }
}

// ---------------------------------------------------------------- k2: main GEMM
// 128x128 tile, BK=32, bf16 MFMA. 2-phase double-buffered async staging
// (1 barrier per K-step). Fused: scores = q.K for kv==0 tiles.
__global__ __launch_bounds__(256) void k2_gemm(
    const u16* __restrict__ kv_raw, const u16* __restrict__ Wbf,
    const float* __restrict__ bk, const float* __restrict__ bv,
    const float* __restrict__ qg,
    u16* __restrict__ mhT, float* __restrict__ s1buf, float* __restrict__ s2buf,
    float* __restrict__ scores, int b0, int BG) {
  __shared__ __align__(16) char ldsbuf[33280];
  __shared__ float qsh[Dn];
  u16* As0 = (u16*)ldsbuf;             // [128 t][32 f]  8KB
  u16* Bs0 = (u16*)(ldsbuf + 8192);    // [128 d][32 f]  8KB
  u16* As1 = (u16*)(ldsbuf + 16384);
  u16* Bs1 = (u16*)(ldsbuf + 24576);
  u16* Cst = (u16*)ldsbuf;             // [128 t][130] (reused after K-loop)
  int tid = threadIdx.x, lane = tid & 63, w = tid >> 6;
  int t0 = blockIdx.x * 128;
  int b_l = blockIdx.y / Hn, h = blockIdx.y % Hn, kv = blockIdx.z;
  int b = b0 + b_l;
  if (tid < Dn) qsh[tid] = qg[h * Dn + tid];
  const u16* Abase = kv_raw + ((size_t)(kv * BG + b_l) * Hn + h) * TPn * Fn + (size_t)t0 * Fn;
  const u16* Bbase = Wbf + ((size_t)(kv * Hn + h)) * Dn * Fn;
  f32x4 acc[4][4];
#pragma unroll
  for (int mi = 0; mi < 4; ++mi)
#pragma unroll
    for (int ni = 0; ni < 4; ++ni) acc[mi][ni] = (f32x4){0.f, 0.f, 0.f, 0.f};
  int wm = (w >> 1) * 64, wn = (w & 1) * 64;
  int lin0 = tid, lin1 = tid + 256;
  int row0 = lin0 >> 2, part0 = lin0 & 3;
  int row1 = lin1 >> 2, part1 = lin1 & 3;
  int wb0 = (w * 64) * 8, wb1 = (256 + w * 64) * 8;  // wave-uniform LDS elem base

  auto STAGE = [&](int f0, u16* Ad, u16* Bd) {
    gload_lds16(Abase + (size_t)row0 * Fn + f0 + part0 * 8, Ad + wb0);
    gload_lds16(Abase + (size_t)row1 * Fn + f0 + part1 * 8, Ad + wb1);
    gload_lds16(Bbase + (size_t)row0 * Fn + f0 + part0 * 8, Bd + wb0);
    gload_lds16(Bbase + (size_t)row1 * Fn + f0 + part1 * 8, Bd + wb1);
  };
  auto COMPUTE = [&](const u16* Ac, const u16* Bc) {
    bf16x8 af[4], bg[4];
#pragma unroll
    for (int mi = 0; mi < 4; ++mi)
      af[mi] = *(const bf16x8*)(Ac + (wm + mi * 16 + (lane & 15)) * 32 + (lane >> 4) * 8);
#pragma unroll
    for (int ni = 0; ni < 4; ++ni)
      bg[ni] = *(const bf16x8*)(Bc + (wn + ni * 16 + (lane & 15)) * 32 + (lane >> 4) * 8);
#pragma unroll
    for (int mi = 0; mi < 4; ++mi)
#pragma unroll
      for (int ni = 0; ni < 4; ++ni)
        acc[mi][ni] = __builtin_amdgcn_mfma_f32_16x16x32_bf16(af[mi], bg[ni], acc[mi][ni], 0, 0, 0);
  };

  STAGE(0, As0, Bs0);
  __syncthreads();  // covers qsh + prologue stage
  for (int f0 = 0; f0 < Fn; f0 += 64) {
    if (f0 + 32 < Fn) STAGE(f0 + 32, As1, Bs1);
    COMPUTE(As0, Bs0);
    __syncthreads();
    if (f0 + 64 < Fn) STAGE(f0 + 64, As0, Bs0);
    COMPUTE(As1, Bs1);
    __syncthreads();
  }

  float bias[4];
  const float* bptr = (kv ? bv : bk) + h * Dn;
#pragma unroll
  for (int ni = 0; ni < 4; ++ni) bias[ni] = bptr[wn + ni * 16 + (lane & 15)];
#pragma unroll
  for (int mi = 0; mi < 4; ++mi)
#pragma unroll
    for (int ni = 0; ni < 4; ++ni)
#pragma unroll
      for (int r = 0; r < 4; ++r) {
        int row = wm + mi * 16 + (lane >> 4) * 4 + r;  // t-local
        int col = wn + ni * 16 + (lane & 15);          // d
        float v = acc[mi][ni][r] + bias[ni];
        if (t0 + row >= Tn) v = 0.f;                   // zero-pad rows (Gram-safe)
        Cst[row * 130 + col] = f2bf(v);
      }
  __syncthreads();
  int d = tid >> 1, half = tid & 1;
  u16* orow = mhT + (((size_t)(kv * Bn + b) * Hn + h) * Dn + d) * TPn + t0;
  float ssum = 0.f, ssq = 0.f;
#pragma unroll
  for (int j = 0; j < 8; ++j) {
    int tb = half * 64 + j * 8;
    u16 pk[8];
#pragma unroll
    for (int ii = 0; ii < 8; ++ii) {
      u16 ub = Cst[(tb + ii) * 130 + d];
      pk[ii] = ub;
      float vr = bf2f(ub);
      ssum += vr;
      ssq += vr * vr;
    }
    uint4 v4;
    v4.x = (unsigned)pk[0] | ((unsigned)pk[1] << 16);
    v4.y = (unsigned)pk[2] | ((unsigned)pk[3] << 16);
    v4.z = (unsigned)pk[4] | ((unsigned)pk[5] << 16);
    v4.w = (unsigned)pk[6] | ((unsigned)pk[7] << 16);
    *reinterpret_cast<uint4*>(orow + tb) = v4;
  }
  int sidx = ((kv * Bn + b) * Hn + h) * Dn + d;
  atomicAdd(&s1buf[sidx], ssum);
  atomicAdd(&s2buf[sidx], ssq);

  // ---- fused attention scores (kv==0 only): s[t] = q . K[t,:]
  if (kv == 0) {
    int t = tid >> 1, hf = tid & 1;
    float s = 0.f;
    const u16* crow = Cst + t * 130 + hf * 64;
    const float* qh = qsh + hf * 64;
#pragma unroll
    for (int dd = 0; dd < 64; ++dd) s += qh[dd] * bf2f(crow[dd]);
    s += __shfl_xor(s, 1);
    if (hf == 0)
      scores[((size_t)b * Hn + h) * TPn + t0 + t] =
          (t0 + t < Tn) ? s * 0.088388347648318447f : -1e30f;
  }
}

// ---------------------------------------------------------------- k34: merged PV + Gram-direct
// blocks 0..255: softmax+PV (d-split x4).
// blocks 256..511: Gram row-quarter (bh, rq): rows [rq*32,+32) x cols [0,128)
//   over full T in-register, normalized in-block, written straight to corr.
__global__ __launch_bounds__(256) void k34(
    const u16* __restrict__ mhT, const float* __restrict__ scores,
    const float* __restrict__ s1buf, const float* __restrict__ s2buf,
    float* __restrict__ o1, float* __restrict__ corr) {
  __shared__ float sc[TPn];
  __shared__ float red[256];
  __shared__ __align__(16) u16 Kt0[1024], Vt0[4096], Kt1[1024], Vt1[4096];
  __shared__ float mkS[32], skS[32], mvS[128], svS[128];
  int tid = threadIdx.x;
  if (blockIdx.x < 256) {
    // ---------------- PV branch
    int bh = blockIdx.x >> 2, dq = blockIdx.x & 3;
    int b = bh >> 3, h = bh & 7;
    const float* srow = scores + (size_t)bh * TPn;
    float4 z4 = *((const float4*)srow + tid);
    float z[4] = {z4.x, z4.y, z4.z, z4.w};
    float m = fmaxf(fmaxf(z[0], z[1]), fmaxf(z[2], z[3]));
    red[tid] = m;
    __syncthreads();
    for (int s = 128; s > 0; s >>= 1) { if (tid < s) red[tid] = fmaxf(red[tid], red[tid + s]); __syncthreads(); }
    m = red[0];
    __syncthreads();
    float lsum = 0.f;
#pragma unroll
    for (int j = 0; j < 4; ++j) {
      float e = __expf(z[j] - m);   // padded t wrote -1e30 -> e==0
      sc[tid * 4 + j] = e;
      lsum += e;
    }
    red[tid] = lsum;
    __syncthreads();
    for (int s = 128; s > 0; s >>= 1) { if (tid < s) red[tid] += red[tid + s]; __syncthreads(); }
    float inv = 1.f / red[0];
    int dl = tid & 31, slice = tid >> 5;
    int d = dq * 32 + dl;
    const u16* Vr = mhT + ((size_t)(1 * Bn + b) * Hn + h) * Dn * TPn + (size_t)d * TPn + slice * 128;
    const float* at = sc + slice * 128;
    float a = 0.f;
#pragma unroll
    for (int i = 0; i < 16; ++i) {
      bf16x8 vv = *(const bf16x8*)(Vr + i * 8);
#pragma unroll
      for (int j = 0; j < 8; ++j) a += at[i * 8 + j] * (float)vv[j];
    }
    __syncthreads();
    red[tid] = a;
    __syncthreads();
    for (int s = 128; s >= 32; s >>= 1) { if (tid < s) red[tid] += red[tid + s]; __syncthreads(); }
    if (tid < 32) o1[((size_t)b * Hn + h) * Dn + dq * 32 + tid] = inv * red[tid];
    return;
  }
  // ---------------- Gram-direct branch
  int id = blockIdx.x - 256;
  int lane = tid & 63, w = tid >> 6;
  int bh = id & 63, rq = id >> 6;   // rq in [0,4): row-quarter
  int b = bh >> 3, h = bh & 7;
  const u16* Kb = mhT + ((size_t)(0 * Bn + b) * Hn + h) * Dn * TPn + (size_t)(rq * 32) * TPn;
  const u16* Vb = mhT + ((size_t)(1 * Bn + b) * Hn + h) * Dn * TPn;
  // stats (s1/s2 complete before this dispatch)
  if (tid < 32) {
    int dd = rq * 32 + tid;
    int sidx = ((0 * Bn + b) * Hn + h) * Dn + dd;
    float a1 = s1buf[sidx], a2 = s2buf[sidx];
    float mu = a1 / (float)Tn;
    float var = (a2 - a1 * a1 / (float)Tn) / (float)(Tn - 1);
    mkS[tid] = mu;
    skS[tid] = sqrtf(fmaxf(var, 0.f)) + 1e-9f;
  } else if (tid < 160) {
    int dd = tid - 32;
    int sidx = ((1 * Bn + b) * Hn + h) * Dn + dd;
    float a1 = s1buf[sidx], a2 = s2buf[sidx];
    float mu = a1 / (float)Tn;
    float var = (a2 - a1 * a1 / (float)Tn) / (float)(Tn - 1);
    mvS[dd] = mu;
    svS[dd] = sqrtf(fmaxf(var, 0.f)) + 1e-9f;
  }
  f32x4 acc[2][2];
#pragma unroll
  for (int mi = 0; mi < 2; ++mi)
#pragma unroll
    for (int ni = 0; ni < 2; ++ni) acc[mi][ni] = (f32x4){0.f, 0.f, 0.f, 0.f};
  int rowK = tid >> 2, partK = tid & 3;          // K-tile: tid<128 -> rows 0..31
  int wbK = (w * 64) * 8;                        // waves 0,1 cover 2KB
  int rowV0 = tid >> 2, partV0 = tid & 3;        // V-tile call 0: rows 0..63
  int rowV1 = (tid + 256) >> 2, partV1 = tid & 3;// call 1: rows 64..127
  int wbV0 = (w * 64) * 8, wbV1 = (256 + w * 64) * 8;

  auto STAGE = [&](int t0, u16* Kd, u16* Vd) {
    if (w < 2)
      gload_lds16(Kb + (size_t)rowK * TPn + t0 + partK * 8, Kd + wbK);
    gload_lds16(Vb + (size_t)rowV0 * TPn + t0 + partV0 * 8, Vd + wbV0);
    gload_lds16(Vb + (size_t)rowV1 * TPn + t0 + partV1 * 8, Vd + wbV1);
  };
  auto COMPUTE = [&](const u16* Kc, const u16* Vc) {
    bf16x8 af[2], bg[2];
#pragma unroll
    for (int mi = 0; mi < 2; ++mi)
      af[mi] = *(const bf16x8*)(Kc + (mi * 16 + (lane & 15)) * 32 + (lane >> 4) * 8);
#pragma unroll
    for (int ni = 0; ni < 2; ++ni)
      bg[ni] = *(const bf16x8*)(Vc + (w * 32 + ni * 16 + (lane & 15)) * 32 + (lane >> 4) * 8);
#pragma unroll
    for (int mi = 0; mi < 2; ++mi)
#pragma unroll
      for (int ni = 0; ni < 2; ++ni)
        acc[mi][ni] = __builtin_amdgcn_mfma_f32_16x16x32_bf16(af[mi], bg[ni], acc[mi][ni], 0, 0, 0);
  };

  STAGE(0, Kt0, Vt0);
  __syncthreads();  // also covers stats
  for (int s = 0; s < TPn; s += 64) {
    if (s + 32 < TPn) STAGE(s + 32, Kt1, Vt1);
    COMPUTE(Kt0, Vt0);
    __syncthreads();
    if (s + 64 < TPn) STAGE(s + 64, Kt0, Vt0);
    COMPUTE(Kt1, Vt1);
    __syncthreads();
  }
  const float invT = 1.f / (float)Tn;
#pragma unroll
  for (int mi = 0; mi < 2; ++mi)
#pragma unroll
    for (int ni = 0; ni < 2; ++ni)
#pragma unroll
      for (int r = 0; r < 4; ++r) {
        int ml = mi * 16 + (lane >> 4) * 4 + r;        // row-local 0..31
        int nn = w * 32 + ni * 16 + (lane & 15);       // col 0..127
        int mm = rq * 32 + ml;
        if (nn > mm) {
          float S = acc[mi][ni][r];
          float cv = (S - (float)Tn * mkS[ml] * mvS[nn]) * invT / (skS[ml] * svS[nn]);
          int cidx = mm * (2 * Dn - mm - 1) / 2 + (nn - mm - 1);
          corr[(size_t)bh * NCOR + cidx] = cv;
        }
      }
}

// ---------------------------------------------------------------- k5a: head proj
__global__ __launch_bounds__(256) void k5_proj(
    const float* __restrict__ corr, const float* __restrict__ Wproj,
    const float* __restrict__ bproj, float* __restrict__ outs) {
  __shared__ float red[8 * 256];
  int tid = threadIdx.x;
  int e = blockIdx.x, h = blockIdx.y;
  const float4* wp4 = (const float4*)(Wproj + ((size_t)h * En + e) * NCOR);
  float accs[8];
#pragma unroll
  for (int b = 0; b < 8; ++b) accs[b] = 0.f;
  for (int k = 0; k < 8; ++k) {
    int c4 = tid + k * 256;
    if (c4 < NCOR / 4) {
      float4 wv = wp4[c4];
#pragma unroll
      for (int b = 0; b < 8; ++b) {
        float4 cv = *((const float4*)(corr + ((size_t)b * Hn + h) * NCOR) + c4);
        accs[b] += wv.x * cv.x + wv.y * cv.y + wv.z * cv.z + wv.w * cv.w;
      }
    }
  }
#pragma unroll
  for (int b = 0; b < 8; ++b) red[b * 256 + tid] = accs[b];
  __syncthreads();
  for (int s = 128; s > 0; s >>= 1) {
    if (tid < s) {
#pragma unroll
      for (int b = 0; b < 8; ++b) red[b * 256 + tid] += red[b * 256 + tid + s];
    }
    __syncthreads();
  }
  if (tid < 8) outs[((size_t)tid * Hn + h) * En + e] = red[tid * 256] + bproj[h * En + e];
}

// ---------------------------------------------------------------- k5b: final mix
__global__ __launch_bounds__(256) void k5_final(
    const float* __restrict__ outs, const float* __restrict__ o1,
    const float* __restrict__ WT, const float* __restrict__ bT,
    const float* __restrict__ Wp, const float* __restrict__ bp,
    float* __restrict__ out) {
  __shared__ float os[2048];
  __shared__ float o1s[1024];
  __shared__ float redF[256], redT[256];
  int tid = threadIdx.x;
  int b = blockIdx.x >> 3, ic = blockIdx.x & 7;
  for (int i = tid; i < 2048; i += 256) os[i] = outs[(size_t)b * 2048 + i];
  for (int i = tid; i < 1024; i += 256) o1s[i] = o1[(size_t)b * 1024 + i];
  __syncthreads();
  int il = tid >> 3, slice = tid & 7;
  int i = ic * 32 + il;
  const float* wpr = Wp + (size_t)i * 2048;
  const float* wtr = WT + (size_t)i * 1024;
  float aF = 0.f, aT = 0.f;
  for (int kk = 0; kk < 256; ++kk) { int j = kk * 8 + slice; aF += os[j] * wpr[j]; }
  for (int kk = 0; kk < 128; ++kk) { int j = kk * 8 + slice; aT += o1s[j] * wtr[j]; }
  redF[tid] = aF; redT[tid] = aT;
  __syncthreads();
  for (int s = 4; s > 0; s >>= 1) {
    if (slice < s) { redF[tid] += redF[tid + s]; redT[tid] += redT[tid + s]; }
    __syncthreads();
  }
  if (slice == 0) {
    float oF = redF[tid] + bp[i];
    float oT = redT[tid] + bT[i];
    out[(size_t)b * En + i] = 0.5f * oF + 0.5f * oT;
  }
}

// ---------------------------------------------------------------- launch
extern "C" void kernel_launch(void* const* d_in, const int* in_sizes, int n_in,
                              void* d_out, int out_size, void* d_ws, size_t ws_size,
                              hipStream_t stream) {
  const float* x     = (const float*)d_in[0];
  const float* wk    = (const float*)d_in[1];
  const float* wv    = (const float*)d_in[2];
  const float* q     = (const float*)d_in[3];
  const float* Wk    = (const float*)d_in[4];
  const float* bk    = (const float*)d_in[5];
  const float* Wv    = (const float*)d_in[6];
  const float* bv    = (const float*)d_in[7];
  const float* Wproj = (const float*)d_in[8];
  const float* bproj = (const float*)d_in[9];
  const float* WT    = (const float*)d_in[10];
  const float* bT    = (const float*)d_in[11];
  const float* Wp    = (const float*)d_in[12];
  const float* bp    = (const float*)d_in[13];
  float* out = (float*)d_out;

  char* ws = (char*)d_ws;
  size_t off = 0;
  auto alloc = [&](size_t bytes) { size_t p = off; off += (bytes + 255) & ~(size_t)255; return p; };
  u16*   Wbf    = (u16*)  (ws + alloc((size_t)2 * Hn * Dn * Fn * 2));
  u16*   mhT    = (u16*)  (ws + alloc((size_t)2 * Bn * Hn * Dn * TPn * 2));
  float* s1     = (float*)(ws + alloc((size_t)2 * Bn * Hn * Dn * 4));
  float* s2     = (float*)(ws + alloc((size_t)2 * Bn * Hn * Dn * 4));
  float* o1     = (float*)(ws + alloc((size_t)Bn * Hn * Dn * 4));
  float* corr   = (float*)(ws + alloc((size_t)Bn * Hn * NCOR * 4));
  float* outs   = (float*)(ws + alloc((size_t)Bn * Hn * En * 4));
  float* scores = (float*)(ws + alloc((size_t)Bn * Hn * TPn * 4));
  size_t fixed = off;
  size_t per_b = (size_t)2 * Hn * TPn * Fn * 2;  // kv_raw per batch: 24 MB
  int BG = 8;
  while (BG > 1 && fixed + (size_t)BG * per_b > ws_size) BG >>= 1;
  u16* kv_raw = (u16*)(ws + fixed);

  for (int b0 = 0; b0 < Bn; b0 += BG) {
    k1_raw<<<dim3(24, 32, BG), 256, 0, stream>>>(x, wk, wv, Wk, Wv, kv_raw, Wbf, s1, s2, b0, BG);
    k2_gemm<<<dim3(8, Hn * BG, 2), 256, 0, stream>>>(kv_raw, Wbf, bk, bv, q, mhT, s1, s2,
                                                     scores, b0, BG);
  }
  k34<<<512, 256, 0, stream>>>(mhT, scores, s1, s2, o1, corr);
  k5_proj<<<dim3(En, Hn), 256, 0, stream>>>(corr, Wproj, bproj, outs);
  k5_final<<<64, 256, 0, stream>>>(outs, o1, WT, bT, Wp, bp, out);
}

// Round 4
// 660.994 us; speedup vs baseline: 1.0625x; 1.0106x over previous
//
#include <hip/hip_runtime.h>
#include <hip/hip_bf16.h>

#define Hn 8
#define Fn 768
#define Dn 128
#define En 256
#define Ln 13
#define Bn 8
#define Tn 1000
#define TPn 1024
#define NCOR 8128

typedef float f32x4 __attribute__((ext_vector_type(4)));
typedef __bf16 bf16x8 __attribute__((ext_vector_type(8)));
typedef unsigned short u16;

static __device__ __forceinline__ u16 f2bf(float f) {
  __hip_bfloat16 h = __float2bfloat16(f);
  return __builtin_bit_cast(u16, h);
}
static __device__ __forceinline__ float bf2f(u16 u) {
  return __bfloat162float(__builtin_bit_cast(__hip_bfloat16, u));
}

// async global->LDS, 16B per lane. LDS dest must be wave-uniform base; HW adds lane*16.
static __device__ __forceinline__ void gload_lds16(const u16* g, u16* lds_wave_base) {
  __builtin_amdgcn_global_load_lds(
      (const __attribute__((address_space(1))) unsigned int*)g,
      (__attribute__((address_space(3))) unsigned int*)lds_wave_base, 16, 0, 0);
}

// ---------------------------------------------------------------- k1: l-reduce (+folded prep)
// GRID: (t-block 32, f-block 24, BG).  t fastest => lin%8 == t-block%8, so ALL
// f-chunks of a given kv_raw row land on the same XCD's L2 and merge into full
// 128B lines before writeback (f-fastest order scattered 64B segments across XCDs).
__global__ __launch_bounds__(256) void k1_raw(
    const float* __restrict__ x,
    const float* __restrict__ wk, const float* __restrict__ wv,
    const float* __restrict__ Wk, const float* __restrict__ Wv,
    u16* __restrict__ kv_raw, u16* __restrict__ Wbf,
    float* __restrict__ s1, float* __restrict__ s2,
    int b0, int BG) {
  __shared__ float kvw[16 * Ln];
  __shared__ u16 res[16 * 32 * 34];  // 34816 B; row stride 34 (17 uints, odd)
  int tid = threadIdx.x;
  if (tid < 16) {
    int kvi = tid >> 3, h = tid & 7;
    const float* w = (kvi ? wv : wk) + h * Ln;
    float m = -1e30f;
    for (int l = 0; l < Ln; ++l) m = fmaxf(m, w[l]);
    float e[Ln], s = 0.f;
    for (int l = 0; l < Ln; ++l) { e[l] = expf(w[l] - m); s += e[l]; }
    for (int l = 0; l < Ln; ++l) kvw[tid * Ln + l] = e[l] / s;
  }
  if (b0 == 0) {  // folded k0 work; only the first batch-group pass
    int nb = gridDim.x * gridDim.y * gridDim.z;
    int lin = blockIdx.x + gridDim.x * (blockIdx.y + gridDim.y * blockIdx.z);
    int n = 2 * Hn * Dn * Fn;  // 1572864 == 6144*256: one elem/thread at BG=8
    for (int i = lin * 256 + tid; i < n; i += nb * 256) {
      float v = (i < Hn * Dn * Fn) ? Wk[i] : Wv[i - Hn * Dn * Fn];
      Wbf[i] = f2bf(v);
    }
    int ns = 2 * Bn * Hn * Dn;
    for (int i = lin * 256 + tid; i < ns; i += nb * 256) { s1[i] = 0.f; s2[i] = 0.f; }
  }
  int t0 = blockIdx.x * 32, f0 = blockIdx.y * 32;
  int b_l = blockIdx.z, b = b0 + b_l;
  int fl = tid & 31, tq = tid >> 5;
  int tbase = t0 + tq * 4;
  bool valid = (tbase < Tn);  // Tn%4==0 -> quads never straddle
  float4 xq[13];
  if (valid) {
    const float4* xp = (const float4*)(x + ((size_t)(b * Fn + f0 + fl) * Tn + tbase) * Ln);
#pragma unroll
    for (int i = 0; i < 13; ++i) xq[i] = xp[i];
  }
  __syncthreads();
  const float* xf = (const float*)xq;
  for (int o = 0; o < 16; ++o) {
    float a0 = 0.f, a1 = 0.f, a2 = 0.f, a3 = 0.f;
    if (valid) {
#pragma unroll
      for (int l = 0; l < Ln; ++l) {
        float w = kvw[o * Ln + l];
        a0 += xf[l] * w;
        a1 += xf[Ln + l] * w;
        a2 += xf[2 * Ln + l] * w;
        a3 += xf[3 * Ln + l] * w;
      }
    }
    int rb = o * 1088 + tq * 4 * 34 + fl;
    res[rb] = f2bf(a0);
    res[rb + 34] = f2bf(a1);
    res[rb + 68] = f2bf(a2);
    res[rb + 102] = f2bf(a3);
  }
  __syncthreads();
  int part = tid & 3;
#pragma unroll
  for (int it = 0; it < 8; ++it) {
    int r = (tid >> 2) + it * 64;
    int o = r >> 5, tl = r & 31;
    int kv = o >> 3, h = o & 7;
    const u16* src = res + o * 1088 + tl * 34 + part * 8;
    uint4 v;
    v.x = *(const unsigned*)(src + 0);
    v.y = *(const unsigned*)(src + 2);
    v.z = *(const unsigned*)(src + 4);
    v.w = *(const unsigned*)(src + 6);
    u16* dst = kv_raw + (((size_t)(kv * BG + b_l) * Hn + h) * TPn + t0 + tl) * Fn + f0 + part * 8;
    *reinterpret_cast<uint4*>(dst) = v;
  }
}

// ---------------------------------------------------------------- k2: main GEMM
// 128x128 tile, BK=32, bf16 MFMA. 2-phase double-buffered async staging
// (1 barrier per K-step). Fused: scores = q.K for kv==0 tiles.
__global__ __launch_bounds__(256) void k2_gemm(
    const u16* __restrict__ kv_raw, const u16* __restrict__ Wbf,
    const float* __restrict__ bk, const float* __restrict__ bv,
    const float* __restrict__ qg,
    u16* __restrict__ mhT, float* __restrict__ s1buf, float* __restrict__ s2buf,
    float* __restrict__ scores, int b0, int BG) {
  __shared__ __align__(16) char ldsbuf[33280];
  __shared__ float qsh[Dn];
  u16* As0 = (u16*)ldsbuf;             // [128 t][32 f]  8KB
  u16* Bs0 = (u16*)(ldsbuf + 8192);    // [128 d][32 f]  8KB
  u16* As1 = (u16*)(ldsbuf + 16384);
  u16* Bs1 = (u16*)(ldsbuf + 24576);
  u16* Cst = (u16*)ldsbuf;             // [128 t][130] (reused after K-loop)
  int tid = threadIdx.x, lane = tid & 63, w = tid >> 6;
  int t0 = blockIdx.x * 128;
  int b_l = blockIdx.y / Hn, h = blockIdx.y % Hn, kv = blockIdx.z;
  int b = b0 + b_l;
  if (tid < Dn) qsh[tid] = qg[h * Dn + tid];
  const u16* Abase = kv_raw + ((size_t)(kv * BG + b_l) * Hn + h) * TPn * Fn + (size_t)t0 * Fn;
  const u16* Bbase = Wbf + ((size_t)(kv * Hn + h)) * Dn * Fn;
  f32x4 acc[4][4];
#pragma unroll
  for (int mi = 0; mi < 4; ++mi)
#pragma unroll
    for (int ni = 0; ni < 4; ++ni) acc[mi][ni] = (f32x4){0.f, 0.f, 0.f, 0.f};
  int wm = (w >> 1) * 64, wn = (w & 1) * 64;
  int lin0 = tid, lin1 = tid + 256;
  int row0 = lin0 >> 2, part0 = lin0 & 3;
  int row1 = lin1 >> 2, part1 = lin1 & 3;
  int wb0 = (w * 64) * 8, wb1 = (256 + w * 64) * 8;  // wave-uniform LDS elem base

  auto STAGE = [&](int f0, u16* Ad, u16* Bd) {
    gload_lds16(Abase + (size_t)row0 * Fn + f0 + part0 * 8, Ad + wb0);
    gload_lds16(Abase + (size_t)row1 * Fn + f0 + part1 * 8, Ad + wb1);
    gload_lds16(Bbase + (size_t)row0 * Fn + f0 + part0 * 8, Bd + wb0);
    gload_lds16(Bbase + (size_t)row1 * Fn + f0 + part1 * 8, Bd + wb1);
  };
  auto COMPUTE = [&](const u16* Ac, const u16* Bc) {
    bf16x8 af[4], bg[4];
#pragma unroll
    for (int mi = 0; mi < 4; ++mi)
      af[mi] = *(const bf16x8*)(Ac + (wm + mi * 16 + (lane & 15)) * 32 + (lane >> 4) * 8);
#pragma unroll
    for (int ni = 0; ni < 4; ++ni)
      bg[ni] = *(const bf16x8*)(Bc + (wn + ni * 16 + (lane & 15)) * 32 + (lane >> 4) * 8);
#pragma unroll
    for (int mi = 0; mi < 4; ++mi)
#pragma unroll
      for (int ni = 0; ni < 4; ++ni)
        acc[mi][ni] = __builtin_amdgcn_mfma_f32_16x16x32_bf16(af[mi], bg[ni], acc[mi][ni], 0, 0, 0);
  };

  STAGE(0, As0, Bs0);
  __syncthreads();  // covers qsh + prologue stage
  for (int f0 = 0; f0 < Fn; f0 += 64) {
    if (f0 + 32 < Fn) STAGE(f0 + 32, As1, Bs1);
    COMPUTE(As0, Bs0);
    __syncthreads();
    if (f0 + 64 < Fn) STAGE(f0 + 64, As0, Bs0);
    COMPUTE(As1, Bs1);
    __syncthreads();
  }

  float bias[4];
  const float* bptr = (kv ? bv : bk) + h * Dn;
#pragma unroll
  for (int ni = 0; ni < 4; ++ni) bias[ni] = bptr[wn + ni * 16 + (lane & 15)];
#pragma unroll
  for (int mi = 0; mi < 4; ++mi)
#pragma unroll
    for (int ni = 0; ni < 4; ++ni)
#pragma unroll
      for (int r = 0; r < 4; ++r) {
        int row = wm + mi * 16 + (lane >> 4) * 4 + r;  // t-local
        int col = wn + ni * 16 + (lane & 15);          // d
        float v = acc[mi][ni][r] + bias[ni];
        if (t0 + row >= Tn) v = 0.f;                   // zero-pad rows (Gram-safe)
        Cst[row * 130 + col] = f2bf(v);
      }
  __syncthreads();
  int d = tid >> 1, half = tid & 1;
  u16* orow = mhT + (((size_t)(kv * Bn + b) * Hn + h) * Dn + d) * TPn + t0;
  float ssum = 0.f, ssq = 0.f;
#pragma unroll
  for (int j = 0; j < 8; ++j) {
    int tb = half * 64 + j * 8;
    u16 pk[8];
#pragma unroll
    for (int ii = 0; ii < 8; ++ii) {
      u16 ub = Cst[(tb + ii) * 130 + d];
      pk[ii] = ub;
      float vr = bf2f(ub);
      ssum += vr;
      ssq += vr * vr;
    }
    uint4 v4;
    v4.x = (unsigned)pk[0] | ((unsigned)pk[1] << 16);
    v4.y = (unsigned)pk[2] | ((unsigned)pk[3] << 16);
    v4.z = (unsigned)pk[4] | ((unsigned)pk[5] << 16);
    v4.w = (unsigned)pk[6] | ((unsigned)pk[7] << 16);
    *reinterpret_cast<uint4*>(orow + tb) = v4;
  }
  int sidx = ((kv * Bn + b) * Hn + h) * Dn + d;
  atomicAdd(&s1buf[sidx], ssum);
  atomicAdd(&s2buf[sidx], ssq);

  // ---- fused attention scores (kv==0 only): s[t] = q . K[t,:]
  if (kv == 0) {
    int t = tid >> 1, hf = tid & 1;
    float s = 0.f;
    const u16* crow = Cst + t * 130 + hf * 64;
    const float* qh = qsh + hf * 64;
#pragma unroll
    for (int dd = 0; dd < 64; ++dd) s += qh[dd] * bf2f(crow[dd]);
    s += __shfl_xor(s, 1);
    if (hf == 0)
      scores[((size_t)b * Hn + h) * TPn + t0 + t] =
          (t0 + t < Tn) ? s * 0.088388347648318447f : -1e30f;
  }
}

// ---------------------------------------------------------------- k34: merged PV + Gram-direct
// blocks 0..255: softmax+PV (d-split x4), wave-shuffle reductions (4 barriers).
// blocks 256..511: Gram row-quarter (bh, rq): rows [rq*32,+32) x cols [0,128)
//   over full T in-register, normalized in-block, written straight to corr.
__global__ __launch_bounds__(256) void k34(
    const u16* __restrict__ mhT, const float* __restrict__ scores,
    const float* __restrict__ s1buf, const float* __restrict__ s2buf,
    float* __restrict__ o1, float* __restrict__ corr) {
  __shared__ float sc[TPn];
  __shared__ float red[256];
  __shared__ __align__(16) u16 Kt0[1024], Vt0[4096], Kt1[1024], Vt1[4096];
  __shared__ float mkS[32], skS[32], mvS[128], svS[128];
  int tid = threadIdx.x;
  int lane = tid & 63, w = tid >> 6;
  if (blockIdx.x < 256) {
    // ---------------- PV branch
    int bh = blockIdx.x >> 2, dq = blockIdx.x & 3;
    int b = bh >> 3, h = bh & 7;
    const float* srow = scores + (size_t)bh * TPn;
    float4 z4 = *((const float4*)srow + tid);
    float z[4] = {z4.x, z4.y, z4.z, z4.w};
    float m = fmaxf(fmaxf(z[0], z[1]), fmaxf(z[2], z[3]));
#pragma unroll
    for (int off = 32; off; off >>= 1) m = fmaxf(m, __shfl_xor(m, off));
    if (lane == 0) red[w] = m;
    __syncthreads();
    m = fmaxf(fmaxf(red[0], red[1]), fmaxf(red[2], red[3]));
    float lsum = 0.f;
#pragma unroll
    for (int j = 0; j < 4; ++j) {
      float e = __expf(z[j] - m);   // padded t wrote -1e30 -> e==0
      sc[tid * 4 + j] = e;
      lsum += e;
    }
#pragma unroll
    for (int off = 32; off; off >>= 1) lsum += __shfl_xor(lsum, off);
    if (lane == 0) red[4 + w] = lsum;
    __syncthreads();
    float inv = 1.f / (red[4] + red[5] + red[6] + red[7]);
    // PV: lane dl handles d = dq*32+dl over t-slice of 128
    int dl = tid & 31, slice = tid >> 5;   // slice == w*2 + (lane>>5)
    int d = dq * 32 + dl;
    const u16* Vr = mhT + ((size_t)(1 * Bn + b) * Hn + h) * Dn * TPn + (size_t)d * TPn + slice * 128;
    const float* at = sc + slice * 128;
    float a = 0.f;
#pragma unroll
    for (int i = 0; i < 16; ++i) {
      bf16x8 vv = *(const bf16x8*)(Vr + i * 8);
#pragma unroll
      for (int j = 0; j < 8; ++j) a += at[i * 8 + j] * (float)vv[j];
    }
    a += __shfl_xor(a, 32);              // sum slice pair within wave
    __syncthreads();                      // all inv-reads done before red reuse
    if (lane < 32) red[w * 32 + dl] = a;  // 4 wave-partials per dl
    __syncthreads();
    if (tid < 32)
      o1[((size_t)b * Hn + h) * Dn + dq * 32 + tid] =
          inv * (red[tid] + red[32 + tid] + red[64 + tid] + red[96 + tid]);
    return;
  }
  // ---------------- Gram-direct branch
  int id = blockIdx.x - 256;
  int bh = id & 63, rq = id >> 6;   // rq in [0,4): row-quarter
  int b = bh >> 3, h = bh & 7;
  const u16* Kb = mhT + ((size_t)(0 * Bn + b) * Hn + h) * Dn * TPn + (size_t)(rq * 32) * TPn;
  const u16* Vb = mhT + ((size_t)(1 * Bn + b) * Hn + h) * Dn * TPn;
  // stats (s1/s2 complete before this dispatch)
  if (tid < 32) {
    int dd = rq * 32 + tid;
    int sidx = ((0 * Bn + b) * Hn + h) * Dn + dd;
    float a1 = s1buf[sidx], a2 = s2buf[sidx];
    float mu = a1 / (float)Tn;
    float var = (a2 - a1 * a1 / (float)Tn) / (float)(Tn - 1);
    mkS[tid] = mu;
    skS[tid] = sqrtf(fmaxf(var, 0.f)) + 1e-9f;
  } else if (tid < 160) {
    int dd = tid - 32;
    int sidx = ((1 * Bn + b) * Hn + h) * Dn + dd;
    float a1 = s1buf[sidx], a2 = s2buf[sidx];
    float mu = a1 / (float)Tn;
    float var = (a2 - a1 * a1 / (float)Tn) / (float)(Tn - 1);
    mvS[dd] = mu;
    svS[dd] = sqrtf(fmaxf(var, 0.f)) + 1e-9f;
  }
  f32x4 acc[2][2];
#pragma unroll
  for (int mi = 0; mi < 2; ++mi)
#pragma unroll
    for (int ni = 0; ni < 2; ++ni) acc[mi][ni] = (f32x4){0.f, 0.f, 0.f, 0.f};
  int rowK = tid >> 2, partK = tid & 3;          // K-tile: tid<128 -> rows 0..31
  int wbK = (w * 64) * 8;                        // waves 0,1 cover 2KB
  int rowV0 = tid >> 2, partV0 = tid & 3;        // V-tile call 0: rows 0..63
  int rowV1 = (tid + 256) >> 2, partV1 = tid & 3;// call 1: rows 64..127
  int wbV0 = (w * 64) * 8, wbV1 = (256 + w * 64) * 8;

  auto STAGE = [&](int t0, u16* Kd, u16* Vd) {
    if (w < 2)
      gload_lds16(Kb + (size_t)rowK * TPn + t0 + partK * 8, Kd + wbK);
    gload_lds16(Vb + (size_t)rowV0 * TPn + t0 + partV0 * 8, Vd + wbV0);
    gload_lds16(Vb + (size_t)rowV1 * TPn + t0 + partV1 * 8, Vd + wbV1);
  };
  auto COMPUTE = [&](const u16* Kc, const u16* Vc) {
    bf16x8 af[2], bg[2];
#pragma unroll
    for (int mi = 0; mi < 2; ++mi)
      af[mi] = *(const bf16x8*)(Kc + (mi * 16 + (lane & 15)) * 32 + (lane >> 4) * 8);
#pragma unroll
    for (int ni = 0; ni < 2; ++ni)
      bg[ni] = *(const bf16x8*)(Vc + (w * 32 + ni * 16 + (lane & 15)) * 32 + (lane >> 4) * 8);
#pragma unroll
    for (int mi = 0; mi < 2; ++mi)
#pragma unroll
      for (int ni = 0; ni < 2; ++ni)
        acc[mi][ni] = __builtin_amdgcn_mfma_f32_16x16x32_bf16(af[mi], bg[ni], acc[mi][ni], 0, 0, 0);
  };

  STAGE(0, Kt0, Vt0);
  __syncthreads();  // also covers stats
  for (int s = 0; s < TPn; s += 64) {
    if (s + 32 < TPn) STAGE(s + 32, Kt1, Vt1);
    COMPUTE(Kt0, Vt0);
    __syncthreads();
    if (s + 64 < TPn) STAGE(s + 64, Kt0, Vt0);
    COMPUTE(Kt1, Vt1);
    __syncthreads();
  }
  const float invT = 1.f / (float)Tn;
#pragma unroll
  for (int mi = 0; mi < 2; ++mi)
#pragma unroll
    for (int ni = 0; ni < 2; ++ni)
#pragma unroll
      for (int r = 0; r < 4; ++r) {
        int ml = mi * 16 + (lane >> 4) * 4 + r;        // row-local 0..31
        int nn = w * 32 + ni * 16 + (lane & 15);       // col 0..127
        int mm = rq * 32 + ml;
        if (nn > mm) {
          float S = acc[mi][ni][r];
          float cv = (S - (float)Tn * mkS[ml] * mvS[nn]) * invT / (skS[ml] * svS[nn]);
          int cidx = mm * (2 * Dn - mm - 1) / 2 + (nn - mm - 1);
          corr[(size_t)bh * NCOR + cidx] = cv;
        }
      }
}

// ---------------------------------------------------------------- k5a: head proj
__global__ __launch_bounds__(256) void k5_proj(
    const float* __restrict__ corr, const float* __restrict__ Wproj,
    const float* __restrict__ bproj, float* __restrict__ outs) {
  __shared__ float red[8 * 256];
  int tid = threadIdx.x;
  int e = blockIdx.x, h = blockIdx.y;
  const float4* wp4 = (const float4*)(Wproj + ((size_t)h * En + e) * NCOR);
  float accs[8];
#pragma unroll
  for (int b = 0; b < 8; ++b) accs[b] = 0.f;
  for (int k = 0; k < 8; ++k) {
    int c4 = tid + k * 256;
    if (c4 < NCOR / 4) {
      float4 wv = wp4[c4];
#pragma unroll
      for (int b = 0; b < 8; ++b) {
        float4 cv = *((const float4*)(corr + ((size_t)b * Hn + h) * NCOR) + c4);
        accs[b] += wv.x * cv.x + wv.y * cv.y + wv.z * cv.z + wv.w * cv.w;
      }
    }
  }
#pragma unroll
  for (int b = 0; b < 8; ++b) red[b * 256 + tid] = accs[b];
  __syncthreads();
  for (int s = 128; s > 0; s >>= 1) {
    if (tid < s) {
#pragma unroll
      for (int b = 0; b < 8; ++b) red[b * 256 + tid] += red[b * 256 + tid + s];
    }
    __syncthreads();
  }
  if (tid < 8) outs[((size_t)tid * Hn + h) * En + e] = red[tid * 256] + bproj[h * En + e];
}

// ---------------------------------------------------------------- k5b: final mix
__global__ __launch_bounds__(256) void k5_final(
    const float* __restrict__ outs, const float* __restrict__ o1,
    const float* __restrict__ WT, const float* __restrict__ bT,
    const float* __restrict__ Wp, const float* __restrict__ bp,
    float* __restrict__ out) {
  __shared__ float os[2048];
  __shared__ float o1s[1024];
  __shared__ float redF[256], redT[256];
  int tid = threadIdx.x;
  int b = blockIdx.x >> 3, ic = blockIdx.x & 7;
  for (int i = tid; i < 2048; i += 256) os[i] = outs[(size_t)b * 2048 + i];
  for (int i = tid; i < 1024; i += 256) o1s[i] = o1[(size_t)b * 1024 + i];
  __syncthreads();
  int il = tid >> 3, slice = tid & 7;
  int i = ic * 32 + il;
  const float* wpr = Wp + (size_t)i * 2048;
  const float* wtr = WT + (size_t)i * 1024;
  float aF = 0.f, aT = 0.f;
  for (int kk = 0; kk < 256; ++kk) { int j = kk * 8 + slice; aF += os[j] * wpr[j]; }
  for (int kk = 0; kk < 128; ++kk) { int j = kk * 8 + slice; aT += o1s[j] * wtr[j]; }
  redF[tid] = aF; redT[tid] = aT;
  __syncthreads();
  for (int s = 4; s > 0; s >>= 1) {
    if (slice < s) { redF[tid] += redF[tid + s]; redT[tid] += redT[tid + s]; }
    __syncthreads();
  }
  if (slice == 0) {
    float oF = redF[tid] + bp[i];
    float oT = redT[tid] + bT[i];
    out[(size_t)b * En + i] = 0.5f * oF + 0.5f * oT;
  }
}

// ---------------------------------------------------------------- launch
extern "C" void kernel_launch(void* const* d_in, const int* in_sizes, int n_in,
                              void* d_out, int out_size, void* d_ws, size_t ws_size,
                              hipStream_t stream) {
  const float* x     = (const float*)d_in[0];
  const float* wk    = (const float*)d_in[1];
  const float* wv    = (const float*)d_in[2];
  const float* q     = (const float*)d_in[3];
  const float* Wk    = (const float*)d_in[4];
  const float* bk    = (const float*)d_in[5];
  const float* Wv    = (const float*)d_in[6];
  const float* bv    = (const float*)d_in[7];
  const float* Wproj = (const float*)d_in[8];
  const float* bproj = (const float*)d_in[9];
  const float* WT    = (const float*)d_in[10];
  const float* bT    = (const float*)d_in[11];
  const float* Wp    = (const float*)d_in[12];
  const float* bp    = (const float*)d_in[13];
  float* out = (float*)d_out;

  char* ws = (char*)d_ws;
  size_t off = 0;
  auto alloc = [&](size_t bytes) { size_t p = off; off += (bytes + 255) & ~(size_t)255; return p; };
  u16*   Wbf    = (u16*)  (ws + alloc((size_t)2 * Hn * Dn * Fn * 2));
  u16*   mhT    = (u16*)  (ws + alloc((size_t)2 * Bn * Hn * Dn * TPn * 2));
  float* s1     = (float*)(ws + alloc((size_t)2 * Bn * Hn * Dn * 4));
  float* s2     = (float*)(ws + alloc((size_t)2 * Bn * Hn * Dn * 4));
  float* o1     = (float*)(ws + alloc((size_t)Bn * Hn * Dn * 4));
  float* corr   = (float*)(ws + alloc((size_t)Bn * Hn * NCOR * 4));
  float* outs   = (float*)(ws + alloc((size_t)Bn * Hn * En * 4));
  float* scores = (float*)(ws + alloc((size_t)Bn * Hn * TPn * 4));
  size_t fixed = off;
  size_t per_b = (size_t)2 * Hn * TPn * Fn * 2;  // kv_raw per batch: 24 MB
  int BG = 8;
  while (BG > 1 && fixed + (size_t)BG * per_b > ws_size) BG >>= 1;
  u16* kv_raw = (u16*)(ws + fixed);

  for (int b0 = 0; b0 < Bn; b0 += BG) {
    k1_raw<<<dim3(32, 24, BG), 256, 0, stream>>>(x, wk, wv, Wk, Wv, kv_raw, Wbf, s1, s2, b0, BG);
    k2_gemm<<<dim3(8, Hn * BG, 2), 256, 0, stream>>>(kv_raw, Wbf, bk, bv, q, mhT, s1, s2,
                                                     scores, b0, BG);
  }
  k34<<<512, 256, 0, stream>>>(mhT, scores, s1, s2, o1, corr);
  k5_proj<<<dim3(En, Hn), 256, 0, stream>>>(corr, Wproj, bproj, outs);
  k5_final<<<64, 256, 0, stream>>>(outs, o1, WT, bT, Wp, bp, out);
}